// Round 1
// baseline (732.601 us; speedup 1.0000x reference)
//
#include <hip/hip_runtime.h>
#include <cstddef>

#define NN 50000
#define EE 800000
#define DIM 128

typedef __attribute__((ext_vector_type(8))) short bf16x8;
typedef __attribute__((ext_vector_type(4))) float f32x4;

// ---------------------------------------------------------------------------
// helpers
// ---------------------------------------------------------------------------
__device__ __forceinline__ unsigned short f2bf(float x) {
    unsigned u = __float_as_uint(x);
    unsigned r = (u + 0x7FFFu + ((u >> 16) & 1u)) >> 16;   // RNE
    return (unsigned short)r;
}

__device__ __forceinline__ int load_idx(const void* ei, bool i64, long long i) {
    return i64 ? (int)((const long long*)ei)[i] : ((const int*)ei)[i];
}

// int64-vs-int32 detection (reference declares int64; JAX x64-off emits int32)
__global__ void detect_i64_kernel(const int* __restrict__ ei, int* __restrict__ flag) {
    int l = threadIdx.x;           // 64 threads
    int v = ei[2 * l + 1];
    unsigned long long b = __ballot(v != 0);
    if (l == 0) flag[0] = (b == 0ULL) ? 1 : 0;
}

// convert W1,W2 (f32, [k][n]) -> bf16 transposed [n][k]
__global__ __launch_bounds__(256) void prep_w_kernel(
    const float* __restrict__ W1, const float* __restrict__ W2,
    unsigned short* __restrict__ W1t, unsigned short* __restrict__ W2t)
{
    int idx = blockIdx.x * 256 + threadIdx.x;     // 32768 total
    int m   = idx >> 14;
    int rem = idx & 16383;
    int n = rem >> 7, k = rem & 127;
    const float* W = m ? W2 : W1;
    unsigned short* Wt = m ? W2t : W1t;
    Wt[n * DIM + k] = f2bf(W[k * DIM + n]);
}

// degree count (int)
__global__ __launch_bounds__(256) void deg_i_kernel(const void* __restrict__ ei,
                                                    const int* __restrict__ flag,
                                                    int* __restrict__ deg) {
    bool i64 = flag[0] != 0;
    int e = blockIdx.x * 256 + threadIdx.x;
    if (e < EE) {
        int r = load_idx(ei, i64, e);              // row = edge_index[0][e]
        atomicAdd(&deg[r], 1);
    }
}

// exclusive prefix scan over deg[NN] -> off[NN]; single block of 256 threads.
__global__ __launch_bounds__(256) void scan_kernel(const int* __restrict__ deg,
                                                   int* __restrict__ off) {
    const int C = (NN + 255) / 256;   // 196 elems per thread, contiguous chunk
    int t = threadIdx.x;
    int base = t * C;
    int sum = 0;
    for (int i = 0; i < C; ++i) {
        int n = base + i;
        if (n < NN) sum += deg[n];
    }
    __shared__ int ps[256];
    ps[t] = sum;
    __syncthreads();
    for (int s = 1; s < 256; s <<= 1) {
        int v = (t >= s) ? ps[t - s] : 0;
        __syncthreads();
        ps[t] += v;
        __syncthreads();
    }
    int run = (t == 0) ? 0 : ps[t - 1];
    for (int i = 0; i < C; ++i) {
        int n = base + i;
        if (n < NN) { off[n] = run; run += deg[n]; }
    }
}

// ---------------------------------------------------------------------------
// Fused message MLP (bf16 MFMA) + CSR slot claim + coalesced bf16 store.
// Block = 256 threads (4 waves); each wave owns 16 edges, full 128 out cols.
// mfma_f32_16x16x32_bf16: A row=l&15, k=8*(l>>4)+i ; B col=l&15, same k ;
// D col=l&15, row=4*(l>>4)+j  (m89-verified).
// Tail: one atomicAdd per edge claims slot = off[r]++ (off becomes segment
// end); message transposed through LDS and written 256B-contiguous per edge.
// ---------------------------------------------------------------------------
__global__ __launch_bounds__(256) void msg_csr_kernel(
    const float* __restrict__ h, const void* __restrict__ ei, const int* __restrict__ flag,
    const unsigned short* __restrict__ W1t, const float* __restrict__ b1,
    const unsigned short* __restrict__ W2t, const float* __restrict__ b2,
    int* __restrict__ off, unsigned short* __restrict__ mbuf)
{
    __shared__ unsigned short xs[4][16][136];   // bf16, +8 pad -> 2-way max
    const int tid  = threadIdx.x;
    const int lane = tid & 63;
    const int wid  = tid >> 6;
    const int g    = lane >> 4;     // k-group
    const int c    = lane & 15;     // col / row-in-tile
    const bool i64 = flag[0] != 0;
    const int ebase = blockIdx.x * 64 + wid * 16;

    // gather source rows, convert f32 -> bf16 into LDS (row = 512B coalesced)
    #pragma unroll
    for (int e = 0; e < 16; ++e) {
        int src = load_idx(ei, i64, (long long)EE + (ebase + e));
        float2 v = *(const float2*)(h + (size_t)src * DIM + lane * 2);
        unsigned p = (unsigned)f2bf(v.x) | ((unsigned)f2bf(v.y) << 16);
        *(unsigned*)&xs[wid][e][lane * 2] = p;
    }
    __syncthreads();

    // ---- layer 1 ----
    bf16x8 a[4];
    #pragma unroll
    for (int s = 0; s < 4; ++s)
        a[s] = *(const bf16x8*)&xs[wid][c][s * 32 + g * 8];

    f32x4 acc[8];
    #pragma unroll
    for (int t = 0; t < 8; ++t) {
        float bv = b1[t * 16 + c];
        acc[t] = (f32x4){bv, bv, bv, bv};
    }
    #pragma unroll
    for (int t = 0; t < 8; ++t) {
        #pragma unroll
        for (int s = 0; s < 4; ++s) {
            bf16x8 bf = *(const bf16x8*)&W1t[(t * 16 + c) * DIM + s * 32 + g * 8];
            acc[t] = __builtin_amdgcn_mfma_f32_16x16x32_bf16(a[s], bf, acc[t], 0, 0, 0);
        }
    }
    __syncthreads();
    // relu + D-layout -> LDS (row = 4g+j, col = 16t+c)
    #pragma unroll
    for (int t = 0; t < 8; ++t)
        #pragma unroll
        for (int j = 0; j < 4; ++j)
            xs[wid][g * 4 + j][t * 16 + c] = f2bf(fmaxf(acc[t][j], 0.f));
    __syncthreads();

    // ---- layer 2 ----
    #pragma unroll
    for (int s = 0; s < 4; ++s)
        a[s] = *(const bf16x8*)&xs[wid][c][s * 32 + g * 8];

    #pragma unroll
    for (int t = 0; t < 8; ++t) {
        float bv = b2[t * 16 + c];
        acc[t] = (f32x4){bv, bv, bv, bv};
    }
    #pragma unroll
    for (int t = 0; t < 8; ++t) {
        #pragma unroll
        for (int s = 0; s < 4; ++s) {
            bf16x8 bf = *(const bf16x8*)&W2t[(t * 16 + c) * DIM + s * 32 + g * 8];
            acc[t] = __builtin_amdgcn_mfma_f32_16x16x32_bf16(a[s], bf, acc[t], 0, 0, 0);
        }
    }

    // claim one slot per edge (lanes 0..15 each own one of the wave's edges)
    int slot = 0;
    if (lane < 16) {
        int r = load_idx(ei, i64, ebase + lane);   // row = edge_index[0][e]
        slot = atomicAdd(&off[r], 1);
    }

    // relu + transpose through LDS to [edge][col] layout
    #pragma unroll
    for (int t = 0; t < 8; ++t)
        #pragma unroll
        for (int j = 0; j < 4; ++j)
            xs[wid][g * 4 + j][t * 16 + c] = f2bf(fmaxf(acc[t][j], 0.f));
    __syncthreads();

    // coalesced bf16 store: 256B per edge (64 lanes x 4B)
    #pragma unroll
    for (int e = 0; e < 16; ++e) {
        int se = __shfl(slot, e);
        unsigned p = *(const unsigned*)&xs[wid][e][lane * 2];
        *(unsigned*)(mbuf + (size_t)se * DIM + lane * 2) = p;
    }
}

// ---------------------------------------------------------------------------
// Old atomic-scatter message kernel — fallback when workspace is too small.
// ---------------------------------------------------------------------------
__global__ __launch_bounds__(256) void msg_kernel(
    const float* __restrict__ h, const void* __restrict__ ei, const int* __restrict__ flag,
    const unsigned short* __restrict__ W1t, const float* __restrict__ b1,
    const unsigned short* __restrict__ W2t, const float* __restrict__ b2,
    float* __restrict__ agg)
{
    __shared__ unsigned short xs[4][16][136];
    const int tid  = threadIdx.x;
    const int lane = tid & 63;
    const int wid  = tid >> 6;
    const int g    = lane >> 4;
    const int c    = lane & 15;
    const bool i64 = flag[0] != 0;
    const int ebase = blockIdx.x * 64 + wid * 16;

    #pragma unroll
    for (int e = 0; e < 16; ++e) {
        int src = load_idx(ei, i64, (long long)EE + (ebase + e));
        float2 v = *(const float2*)(h + (size_t)src * DIM + lane * 2);
        unsigned p = (unsigned)f2bf(v.x) | ((unsigned)f2bf(v.y) << 16);
        *(unsigned*)&xs[wid][e][lane * 2] = p;
    }
    __syncthreads();

    bf16x8 a[4];
    #pragma unroll
    for (int s = 0; s < 4; ++s)
        a[s] = *(const bf16x8*)&xs[wid][c][s * 32 + g * 8];

    f32x4 acc[8];
    #pragma unroll
    for (int t = 0; t < 8; ++t) {
        float bv = b1[t * 16 + c];
        acc[t] = (f32x4){bv, bv, bv, bv};
    }
    #pragma unroll
    for (int t = 0; t < 8; ++t) {
        #pragma unroll
        for (int s = 0; s < 4; ++s) {
            bf16x8 bf = *(const bf16x8*)&W1t[(t * 16 + c) * DIM + s * 32 + g * 8];
            acc[t] = __builtin_amdgcn_mfma_f32_16x16x32_bf16(a[s], bf, acc[t], 0, 0, 0);
        }
    }
    __syncthreads();
    #pragma unroll
    for (int t = 0; t < 8; ++t)
        #pragma unroll
        for (int j = 0; j < 4; ++j)
            xs[wid][g * 4 + j][t * 16 + c] = f2bf(fmaxf(acc[t][j], 0.f));
    __syncthreads();

    #pragma unroll
    for (int s = 0; s < 4; ++s)
        a[s] = *(const bf16x8*)&xs[wid][c][s * 32 + g * 8];

    #pragma unroll
    for (int t = 0; t < 8; ++t) {
        float bv = b2[t * 16 + c];
        acc[t] = (f32x4){bv, bv, bv, bv};
    }
    #pragma unroll
    for (int t = 0; t < 8; ++t) {
        #pragma unroll
        for (int s = 0; s < 4; ++s) {
            bf16x8 bf = *(const bf16x8*)&W2t[(t * 16 + c) * DIM + s * 32 + g * 8];
            acc[t] = __builtin_amdgcn_mfma_f32_16x16x32_bf16(a[s], bf, acc[t], 0, 0, 0);
        }
    }

    #pragma unroll
    for (int j = 0; j < 4; ++j) {
        int r = load_idx(ei, i64, ebase + g * 4 + j);
        #pragma unroll
        for (int t = 0; t < 8; ++t)
            atomicAdd(&agg[(size_t)r * DIM + t * 16 + c], fmaxf(acc[t][j], 0.f));
    }
}

// ---------------------------------------------------------------------------
// Segment reduce: one wave per node, streams contiguous bf16 messages.
// off_end[n] = segment end (mutated offsets); start = end - deg[n].
// ---------------------------------------------------------------------------
__global__ __launch_bounds__(256) void reduce_kernel(
    const unsigned short* __restrict__ mbuf, const int* __restrict__ off_end,
    const int* __restrict__ deg, float* __restrict__ agg)
{
    int wv = blockIdx.x * 4 + (threadIdx.x >> 6);   // node id
    int lane = threadIdx.x & 63;
    if (wv >= NN) return;
    int end = off_end[wv];
    int d = deg[wv];
    int start = end - d;
    const unsigned short* p = mbuf + (size_t)start * DIM + lane * 2;
    float a0 = 0.f, a1 = 0.f, b0 = 0.f, b1 = 0.f;
    int i = 0;
    for (; i + 2 <= d; i += 2) {
        unsigned u0 = *(const unsigned*)p;
        unsigned u1 = *(const unsigned*)(p + DIM);
        p += 2 * DIM;
        a0 += __uint_as_float(u0 << 16);
        a1 += __uint_as_float(u0 & 0xFFFF0000u);
        b0 += __uint_as_float(u1 << 16);
        b1 += __uint_as_float(u1 & 0xFFFF0000u);
    }
    if (i < d) {
        unsigned u0 = *(const unsigned*)p;
        a0 += __uint_as_float(u0 << 16);
        a1 += __uint_as_float(u0 & 0xFFFF0000u);
    }
    float2 o;
    o.x = a0 + b0;
    o.y = a1 + b1;
    *(float2*)(agg + (size_t)wv * DIM + lane * 2) = o;
}

// ---------------------------------------------------------------------------
// Update MLP (fp32 vector): z=[h, agg/deg] -> relu(z@U1+c1) @U2+c2
// ---------------------------------------------------------------------------
__global__ __launch_bounds__(256) void upd_kernel(
    const float* __restrict__ h, const float* __restrict__ aggout,
    const int* __restrict__ deg,
    const float* __restrict__ U1, const float* __restrict__ c1,
    const float* __restrict__ U2, const float* __restrict__ c2,
    float* __restrict__ out)
{
    __shared__ float zs[4][8][2 * DIM];   // 32 KiB
    const int tid  = threadIdx.x;
    const int lane = tid & 63;
    const int wid  = tid >> 6;
    const int nbase = blockIdx.x * 32 + wid * 8;

    #pragma unroll
    for (int i = 0; i < 8; ++i) {
        int n = nbase + i;
        if (n < NN) {
            float2 hv = *(const float2*)(h + (size_t)n * DIM + lane * 2);
            *(float2*)&zs[wid][i][lane * 2] = hv;
            float d = fmaxf((float)deg[n], 1.0f);
            float inv = 1.0f / d;
            float2 av = *(const float2*)(aggout + (size_t)n * DIM + lane * 2);
            av.x *= inv; av.y *= inv;
            *(float2*)&zs[wid][i][DIM + lane * 2] = av;
        }
    }
    __syncthreads();

    float acc0[8], acc1[8];
    {
        float cc0 = c1[lane], cc1 = c1[lane + 64];
        #pragma unroll
        for (int i = 0; i < 8; ++i) { acc0[i] = cc0; acc1[i] = cc1; }
    }
    for (int k = 0; k < 2 * DIM; k += 4) {
        float wa[4], wb[4];
        #pragma unroll
        for (int kk = 0; kk < 4; ++kk) {
            wa[kk] = U1[(k + kk) * DIM + lane];
            wb[kk] = U1[(k + kk) * DIM + lane + 64];
        }
        #pragma unroll
        for (int i = 0; i < 8; ++i) {
            float4 zv = *(const float4*)&zs[wid][i][k];
            acc0[i] = fmaf(zv.x, wa[0], acc0[i]);
            acc1[i] = fmaf(zv.x, wb[0], acc1[i]);
            acc0[i] = fmaf(zv.y, wa[1], acc0[i]);
            acc1[i] = fmaf(zv.y, wb[1], acc1[i]);
            acc0[i] = fmaf(zv.z, wa[2], acc0[i]);
            acc1[i] = fmaf(zv.z, wb[2], acc1[i]);
            acc0[i] = fmaf(zv.w, wa[3], acc0[i]);
            acc1[i] = fmaf(zv.w, wb[3], acc1[i]);
        }
    }
    __syncthreads();
    #pragma unroll
    for (int i = 0; i < 8; ++i) {
        zs[wid][i][lane]      = fmaxf(acc0[i], 0.f);
        zs[wid][i][lane + 64] = fmaxf(acc1[i], 0.f);
    }
    __syncthreads();

    {
        float cc0 = c2[lane], cc1 = c2[lane + 64];
        #pragma unroll
        for (int i = 0; i < 8; ++i) { acc0[i] = cc0; acc1[i] = cc1; }
    }
    for (int k = 0; k < DIM; k += 4) {
        float wa[4], wb[4];
        #pragma unroll
        for (int kk = 0; kk < 4; ++kk) {
            wa[kk] = U2[(k + kk) * DIM + lane];
            wb[kk] = U2[(k + kk) * DIM + lane + 64];
        }
        #pragma unroll
        for (int i = 0; i < 8; ++i) {
            float4 zv = *(const float4*)&zs[wid][i][k];
            acc0[i] = fmaf(zv.x, wa[0], acc0[i]);
            acc1[i] = fmaf(zv.x, wb[0], acc1[i]);
            acc0[i] = fmaf(zv.y, wa[1], acc0[i]);
            acc1[i] = fmaf(zv.y, wb[1], acc1[i]);
            acc0[i] = fmaf(zv.z, wa[2], acc0[i]);
            acc1[i] = fmaf(zv.z, wb[2], acc1[i]);
            acc0[i] = fmaf(zv.w, wa[3], acc0[i]);
            acc1[i] = fmaf(zv.w, wb[3], acc1[i]);
        }
    }

    #pragma unroll
    for (int i = 0; i < 8; ++i) {
        int n = nbase + i;
        if (n < NN) {
            out[(size_t)n * DIM + lane]      = acc0[i];
            out[(size_t)n * DIM + lane + 64] = acc1[i];
        }
    }
}

extern "C" void kernel_launch(void* const* d_in, const int* in_sizes, int n_in,
                              void* d_out, int out_size, void* d_ws, size_t ws_size,
                              hipStream_t stream) {
    const float* h  = (const float*)d_in[0];
    const void*  ei = d_in[1];
    const float* W1 = (const float*)d_in[2];
    const float* b1 = (const float*)d_in[3];
    const float* W2 = (const float*)d_in[4];
    const float* b2 = (const float*)d_in[5];
    const float* U1 = (const float*)d_in[6];
    const float* c1 = (const float*)d_in[7];
    const float* U2 = (const float*)d_in[8];
    const float* c2 = (const float*)d_in[9];
    float* out = (float*)d_out;

    // ws layout:
    //   big path:  mbuf [0, 204800000) | deg | off | flag | W1t | W2t
    //   fallback:  deg @0 | off | flag | W1t | W2t
    const size_t MBUF_BYTES = (size_t)EE * DIM * sizeof(unsigned short); // 204,800,000
    const size_t META_BYTES = 200000 + 200000 + 64 + 2 * 32768;          // 465,600
    const bool big = ws_size >= MBUF_BYTES + META_BYTES;

    char* base = (char*)d_ws + (big ? MBUF_BYTES : 0);
    int*  deg  = (int*)base;
    int*  off  = (int*)(base + 200000);
    int*  flag = (int*)(base + 400000);
    unsigned short* W1t = (unsigned short*)(base + 400064);
    unsigned short* W2t = (unsigned short*)(base + 400064 + 32768);
    unsigned short* mbuf = (unsigned short*)d_ws;

    detect_i64_kernel<<<1, 64, 0, stream>>>((const int*)ei, flag);
    prep_w_kernel<<<128, 256, 0, stream>>>(W1, W2, W1t, W2t);
    hipMemsetAsync(deg, 0, (size_t)NN * sizeof(int), stream);
    deg_i_kernel<<<(EE + 255) / 256, 256, 0, stream>>>(ei, flag, deg);

    if (big) {
        scan_kernel<<<1, 256, 0, stream>>>(deg, off);
        msg_csr_kernel<<<EE / 64, 256, 0, stream>>>(h, ei, flag, W1t, b1, W2t, b2, off, mbuf);
        reduce_kernel<<<(NN + 3) / 4, 256, 0, stream>>>(mbuf, off, deg, out);
    } else {
        hipMemsetAsync(d_out, 0, (size_t)NN * DIM * sizeof(float), stream);
        msg_kernel<<<EE / 64, 256, 0, stream>>>(h, ei, flag, W1t, b1, W2t, b2, out);
    }
    upd_kernel<<<(NN + 31) / 32, 256, 0, stream>>>(h, out, deg, U1, c1, U2, c2, out);
}

// Round 2
// 304.764 us; speedup vs baseline: 2.4038x; 2.4038x over previous
//
#include <hip/hip_runtime.h>
#include <cstddef>

#define NN 50000
#define EE 800000
#define DIM 128

typedef __attribute__((ext_vector_type(8))) short bf16x8;
typedef __attribute__((ext_vector_type(4))) float f32x4;

// ---------------------------------------------------------------------------
// helpers
// ---------------------------------------------------------------------------
__device__ __forceinline__ unsigned short f2bf(float x) {
    unsigned u = __float_as_uint(x);
    unsigned r = (u + 0x7FFFu + ((u >> 16) & 1u)) >> 16;   // RNE
    return (unsigned short)r;
}

__device__ __forceinline__ int load_idx(const void* ei, bool i64, long long i) {
    return i64 ? (int)((const long long*)ei)[i] : ((const int*)ei)[i];
}

// int64-vs-int32 detection (reference declares int64; JAX x64-off emits int32)
__global__ void detect_i64_kernel(const int* __restrict__ ei, int* __restrict__ flag) {
    int l = threadIdx.x;           // 64 threads
    int v = ei[2 * l + 1];
    unsigned long long b = __ballot(v != 0);
    if (l == 0) flag[0] = (b == 0ULL) ? 1 : 0;
}

// convert W1,W2 (f32, [k][n]) -> bf16 transposed [n][k]
__global__ __launch_bounds__(256) void prep_w_kernel(
    const float* __restrict__ W1, const float* __restrict__ W2,
    unsigned short* __restrict__ W1t, unsigned short* __restrict__ W2t)
{
    int idx = blockIdx.x * 256 + threadIdx.x;     // 32768 total
    int m   = idx >> 14;
    int rem = idx & 16383;
    int n = rem >> 7, k = rem & 127;
    const float* W = m ? W2 : W1;
    unsigned short* Wt = m ? W2t : W1t;
    Wt[n * DIM + k] = f2bf(W[k * DIM + n]);
}

// degree count (int)
__global__ __launch_bounds__(256) void deg_i_kernel(const void* __restrict__ ei,
                                                    const int* __restrict__ flag,
                                                    int* __restrict__ deg) {
    bool i64 = flag[0] != 0;
    int e = blockIdx.x * 256 + threadIdx.x;
    if (e < EE) {
        int r = load_idx(ei, i64, e);              // row = edge_index[0][e]
        atomicAdd(&deg[r], 1);
    }
}

// exclusive prefix scan over deg[NN] -> off[NN]; single block of 256 threads.
// int4-vectorized both passes (only thread 255 takes the scalar tail).
__global__ __launch_bounds__(256) void scan_kernel(const int* __restrict__ deg,
                                                   int* __restrict__ off) {
    const int C = 196;                 // 256*196 = 50176 >= NN
    int t = threadIdx.x;
    int base = t * C;
    int sum = 0;
    if (base + C <= NN) {
        const int4* p = (const int4*)(deg + base);
        #pragma unroll 7
        for (int i = 0; i < C / 4; ++i) { int4 v = p[i]; sum += v.x + v.y + v.z + v.w; }
    } else {
        for (int i = 0; i < C; ++i) { int n = base + i; if (n < NN) sum += deg[n]; }
    }
    __shared__ int ps[256];
    ps[t] = sum;
    __syncthreads();
    for (int s = 1; s < 256; s <<= 1) {
        int v = (t >= s) ? ps[t - s] : 0;
        __syncthreads();
        ps[t] += v;
        __syncthreads();
    }
    int run = (t == 0) ? 0 : ps[t - 1];
    if (base + C <= NN) {
        const int4* dp = (const int4*)(deg + base);
        int4* op = (int4*)(off + base);
        for (int i = 0; i < C / 4; ++i) {
            int4 v = dp[i];
            int4 o;
            o.x = run; run += v.x;
            o.y = run; run += v.y;
            o.z = run; run += v.z;
            o.w = run; run += v.w;
            op[i] = o;
        }
    } else {
        for (int i = 0; i < C; ++i) {
            int n = base + i;
            if (n < NN) { off[n] = run; run += deg[n]; }
        }
    }
}

// slot claim: off[r]++ becomes segment end; col32[slot] = source node (int32)
__global__ __launch_bounds__(256) void fill_kernel(const void* __restrict__ ei,
                                                   const int* __restrict__ flag,
                                                   int* __restrict__ off,
                                                   int* __restrict__ col32) {
    bool i64 = flag[0] != 0;
    int e = blockIdx.x * 256 + threadIdx.x;
    if (e < EE) {
        int r = load_idx(ei, i64, e);
        int c = load_idx(ei, i64, (long long)EE + e);
        int slot = atomicAdd(&off[r], 1);
        col32[slot] = c;
    }
}

// ---------------------------------------------------------------------------
// Node-level message MLP: Mh[n] = relu(relu(h[n]@W1+b1)@W2+b2), bf16 out.
// Message MLP depends only on the SOURCE node -> compute once per node
// (50k rows) instead of once per edge (800k rows). No gather: rows are
// consecutive. LDS tile is wave-private -> no __syncthreads at all.
// mfma_f32_16x16x32_bf16: A row=l&15, k=8*(l>>4)+i ; B col=l&15, same k ;
// D col=l&15, row=4*(l>>4)+j  (m89-verified).
// ---------------------------------------------------------------------------
__global__ __launch_bounds__(256) void node_mlp_kernel(
    const float* __restrict__ h,
    const unsigned short* __restrict__ W1t, const float* __restrict__ b1,
    const unsigned short* __restrict__ W2t, const float* __restrict__ b2,
    unsigned short* __restrict__ Mh)
{
    __shared__ unsigned short xs[4][16][136];   // bf16, +8 pad
    const int tid  = threadIdx.x;
    const int lane = tid & 63;
    const int wid  = tid >> 6;
    const int g    = lane >> 4;     // k-group
    const int c    = lane & 15;     // col / row-in-tile
    const int nbase = blockIdx.x * 64 + wid * 16;

    // load 16 consecutive node rows, f32 -> bf16 into LDS (512B coalesced)
    #pragma unroll
    for (int e = 0; e < 16; ++e) {
        int n = nbase + e;
        int nc = n < NN ? n : NN - 1;
        float2 v = *(const float2*)(h + (size_t)nc * DIM + lane * 2);
        unsigned p = (unsigned)f2bf(v.x) | ((unsigned)f2bf(v.y) << 16);
        *(unsigned*)&xs[wid][e][lane * 2] = p;
    }

    // ---- layer 1 ----
    bf16x8 a[4];
    #pragma unroll
    for (int s = 0; s < 4; ++s)
        a[s] = *(const bf16x8*)&xs[wid][c][s * 32 + g * 8];

    f32x4 acc[8];
    #pragma unroll
    for (int t = 0; t < 8; ++t) {
        float bv = b1[t * 16 + c];
        acc[t] = (f32x4){bv, bv, bv, bv};
    }
    #pragma unroll
    for (int t = 0; t < 8; ++t) {
        #pragma unroll
        for (int s = 0; s < 4; ++s) {
            bf16x8 bf = *(const bf16x8*)&W1t[(t * 16 + c) * DIM + s * 32 + g * 8];
            acc[t] = __builtin_amdgcn_mfma_f32_16x16x32_bf16(a[s], bf, acc[t], 0, 0, 0);
        }
    }
    // relu + D-layout -> LDS (row = 4g+j, col = 16t+c)
    #pragma unroll
    for (int t = 0; t < 8; ++t)
        #pragma unroll
        for (int j = 0; j < 4; ++j)
            xs[wid][g * 4 + j][t * 16 + c] = f2bf(fmaxf(acc[t][j], 0.f));

    // ---- layer 2 ----
    #pragma unroll
    for (int s = 0; s < 4; ++s)
        a[s] = *(const bf16x8*)&xs[wid][c][s * 32 + g * 8];

    #pragma unroll
    for (int t = 0; t < 8; ++t) {
        float bv = b2[t * 16 + c];
        acc[t] = (f32x4){bv, bv, bv, bv};
    }
    #pragma unroll
    for (int t = 0; t < 8; ++t) {
        #pragma unroll
        for (int s = 0; s < 4; ++s) {
            bf16x8 bf = *(const bf16x8*)&W2t[(t * 16 + c) * DIM + s * 32 + g * 8];
            acc[t] = __builtin_amdgcn_mfma_f32_16x16x32_bf16(a[s], bf, acc[t], 0, 0, 0);
        }
    }

    // relu + transpose through LDS to [row][col] layout, then coalesced store
    #pragma unroll
    for (int t = 0; t < 8; ++t)
        #pragma unroll
        for (int j = 0; j < 4; ++j)
            xs[wid][g * 4 + j][t * 16 + c] = f2bf(fmaxf(acc[t][j], 0.f));

    #pragma unroll
    for (int e = 0; e < 16; ++e) {
        int n = nbase + e;
        if (n < NN)
            *(unsigned*)(Mh + (size_t)n * DIM + lane * 2) = *(const unsigned*)&xs[wid][e][lane * 2];
    }
}

// ---------------------------------------------------------------------------
// Gather-sum: one wave per node; agg[n] = sum over its edges of Mh[col].
// Mh is 12.8 MB (L2/L3 resident). 4 gathers in flight per iteration.
// off_end[n] = segment end (mutated offsets); start = end - deg[n].
// ---------------------------------------------------------------------------
__global__ __launch_bounds__(256) void gather_reduce_kernel(
    const unsigned short* __restrict__ Mh, const int* __restrict__ col32,
    const int* __restrict__ off_end, const int* __restrict__ deg,
    float* __restrict__ agg)
{
    int n = blockIdx.x * 4 + (threadIdx.x >> 6);
    int lane = threadIdx.x & 63;
    if (n >= NN) return;
    int d = deg[n];
    int end = off_end[n];
    int start = end - d;

    float a0 = 0.f, a1 = 0.f, b0 = 0.f, b1 = 0.f;
    float c0 = 0.f, c1 = 0.f, d0 = 0.f, d1 = 0.f;
    for (int base = 0; base < d; base += 64) {
        int m = d - base; if (m > 64) m = 64;
        int idx = (lane < m) ? col32[start + base + lane] : 0;
        int j = 0;
        for (; j + 4 <= m; j += 4) {
            int s0 = __shfl(idx, j);
            int s1 = __shfl(idx, j + 1);
            int s2 = __shfl(idx, j + 2);
            int s3 = __shfl(idx, j + 3);
            unsigned u0 = *(const unsigned*)(Mh + (size_t)s0 * DIM + lane * 2);
            unsigned u1 = *(const unsigned*)(Mh + (size_t)s1 * DIM + lane * 2);
            unsigned u2 = *(const unsigned*)(Mh + (size_t)s2 * DIM + lane * 2);
            unsigned u3 = *(const unsigned*)(Mh + (size_t)s3 * DIM + lane * 2);
            a0 += __uint_as_float(u0 << 16);
            a1 += __uint_as_float(u0 & 0xFFFF0000u);
            b0 += __uint_as_float(u1 << 16);
            b1 += __uint_as_float(u1 & 0xFFFF0000u);
            c0 += __uint_as_float(u2 << 16);
            c1 += __uint_as_float(u2 & 0xFFFF0000u);
            d0 += __uint_as_float(u3 << 16);
            d1 += __uint_as_float(u3 & 0xFFFF0000u);
        }
        for (; j < m; ++j) {
            int s0 = __shfl(idx, j);
            unsigned u0 = *(const unsigned*)(Mh + (size_t)s0 * DIM + lane * 2);
            a0 += __uint_as_float(u0 << 16);
            a1 += __uint_as_float(u0 & 0xFFFF0000u);
        }
    }
    float2 o;
    o.x = (a0 + b0) + (c0 + d0);
    o.y = (a1 + b1) + (c1 + d1);
    *(float2*)(agg + (size_t)n * DIM + lane * 2) = o;
}

// ---------------------------------------------------------------------------
// Old atomic-scatter message kernel — fallback when workspace is too small.
// ---------------------------------------------------------------------------
__global__ __launch_bounds__(256) void msg_kernel(
    const float* __restrict__ h, const void* __restrict__ ei, const int* __restrict__ flag,
    const unsigned short* __restrict__ W1t, const float* __restrict__ b1,
    const unsigned short* __restrict__ W2t, const float* __restrict__ b2,
    float* __restrict__ agg)
{
    __shared__ unsigned short xs[4][16][136];
    const int tid  = threadIdx.x;
    const int lane = tid & 63;
    const int wid  = tid >> 6;
    const int g    = lane >> 4;
    const int c    = lane & 15;
    const bool i64 = flag[0] != 0;
    const int ebase = blockIdx.x * 64 + wid * 16;

    #pragma unroll
    for (int e = 0; e < 16; ++e) {
        int src = load_idx(ei, i64, (long long)EE + (ebase + e));
        float2 v = *(const float2*)(h + (size_t)src * DIM + lane * 2);
        unsigned p = (unsigned)f2bf(v.x) | ((unsigned)f2bf(v.y) << 16);
        *(unsigned*)&xs[wid][e][lane * 2] = p;
    }
    __syncthreads();

    bf16x8 a[4];
    #pragma unroll
    for (int s = 0; s < 4; ++s)
        a[s] = *(const bf16x8*)&xs[wid][c][s * 32 + g * 8];

    f32x4 acc[8];
    #pragma unroll
    for (int t = 0; t < 8; ++t) {
        float bv = b1[t * 16 + c];
        acc[t] = (f32x4){bv, bv, bv, bv};
    }
    #pragma unroll
    for (int t = 0; t < 8; ++t) {
        #pragma unroll
        for (int s = 0; s < 4; ++s) {
            bf16x8 bf = *(const bf16x8*)&W1t[(t * 16 + c) * DIM + s * 32 + g * 8];
            acc[t] = __builtin_amdgcn_mfma_f32_16x16x32_bf16(a[s], bf, acc[t], 0, 0, 0);
        }
    }
    __syncthreads();
    #pragma unroll
    for (int t = 0; t < 8; ++t)
        #pragma unroll
        for (int j = 0; j < 4; ++j)
            xs[wid][g * 4 + j][t * 16 + c] = f2bf(fmaxf(acc[t][j], 0.f));
    __syncthreads();

    #pragma unroll
    for (int s = 0; s < 4; ++s)
        a[s] = *(const bf16x8*)&xs[wid][c][s * 32 + g * 8];

    #pragma unroll
    for (int t = 0; t < 8; ++t) {
        float bv = b2[t * 16 + c];
        acc[t] = (f32x4){bv, bv, bv, bv};
    }
    #pragma unroll
    for (int t = 0; t < 8; ++t) {
        #pragma unroll
        for (int s = 0; s < 4; ++s) {
            bf16x8 bf = *(const bf16x8*)&W2t[(t * 16 + c) * DIM + s * 32 + g * 8];
            acc[t] = __builtin_amdgcn_mfma_f32_16x16x32_bf16(a[s], bf, acc[t], 0, 0, 0);
        }
    }

    #pragma unroll
    for (int j = 0; j < 4; ++j) {
        int r = load_idx(ei, i64, ebase + g * 4 + j);
        #pragma unroll
        for (int t = 0; t < 8; ++t)
            atomicAdd(&agg[(size_t)r * DIM + t * 16 + c], fmaxf(acc[t][j], 0.f));
    }
}

// ---------------------------------------------------------------------------
// Update MLP (fp32 vector): z=[h, agg/deg] -> relu(z@U1+c1) @U2+c2
// ---------------------------------------------------------------------------
__global__ __launch_bounds__(256) void upd_kernel(
    const float* __restrict__ h, const float* __restrict__ aggout,
    const int* __restrict__ deg,
    const float* __restrict__ U1, const float* __restrict__ c1,
    const float* __restrict__ U2, const float* __restrict__ c2,
    float* __restrict__ out)
{
    __shared__ float zs[4][8][2 * DIM];   // 32 KiB
    const int tid  = threadIdx.x;
    const int lane = tid & 63;
    const int wid  = tid >> 6;
    const int nbase = blockIdx.x * 32 + wid * 8;

    #pragma unroll
    for (int i = 0; i < 8; ++i) {
        int n = nbase + i;
        if (n < NN) {
            float2 hv = *(const float2*)(h + (size_t)n * DIM + lane * 2);
            *(float2*)&zs[wid][i][lane * 2] = hv;
            float d = fmaxf((float)deg[n], 1.0f);
            float inv = 1.0f / d;
            float2 av = *(const float2*)(aggout + (size_t)n * DIM + lane * 2);
            av.x *= inv; av.y *= inv;
            *(float2*)&zs[wid][i][DIM + lane * 2] = av;
        }
    }
    __syncthreads();

    float acc0[8], acc1[8];
    {
        float cc0 = c1[lane], cc1 = c1[lane + 64];
        #pragma unroll
        for (int i = 0; i < 8; ++i) { acc0[i] = cc0; acc1[i] = cc1; }
    }
    for (int k = 0; k < 2 * DIM; k += 4) {
        float wa[4], wb[4];
        #pragma unroll
        for (int kk = 0; kk < 4; ++kk) {
            wa[kk] = U1[(k + kk) * DIM + lane];
            wb[kk] = U1[(k + kk) * DIM + lane + 64];
        }
        #pragma unroll
        for (int i = 0; i < 8; ++i) {
            float4 zv = *(const float4*)&zs[wid][i][k];
            acc0[i] = fmaf(zv.x, wa[0], acc0[i]);
            acc1[i] = fmaf(zv.x, wb[0], acc1[i]);
            acc0[i] = fmaf(zv.y, wa[1], acc0[i]);
            acc1[i] = fmaf(zv.y, wb[1], acc1[i]);
            acc0[i] = fmaf(zv.z, wa[2], acc0[i]);
            acc1[i] = fmaf(zv.z, wb[2], acc1[i]);
            acc0[i] = fmaf(zv.w, wa[3], acc0[i]);
            acc1[i] = fmaf(zv.w, wb[3], acc1[i]);
        }
    }
    __syncthreads();
    #pragma unroll
    for (int i = 0; i < 8; ++i) {
        zs[wid][i][lane]      = fmaxf(acc0[i], 0.f);
        zs[wid][i][lane + 64] = fmaxf(acc1[i], 0.f);
    }
    __syncthreads();

    {
        float cc0 = c2[lane], cc1 = c2[lane + 64];
        #pragma unroll
        for (int i = 0; i < 8; ++i) { acc0[i] = cc0; acc1[i] = cc1; }
    }
    for (int k = 0; k < DIM; k += 4) {
        float wa[4], wb[4];
        #pragma unroll
        for (int kk = 0; kk < 4; ++kk) {
            wa[kk] = U2[(k + kk) * DIM + lane];
            wb[kk] = U2[(k + kk) * DIM + lane + 64];
        }
        #pragma unroll
        for (int i = 0; i < 8; ++i) {
            float4 zv = *(const float4*)&zs[wid][i][k];
            acc0[i] = fmaf(zv.x, wa[0], acc0[i]);
            acc1[i] = fmaf(zv.x, wb[0], acc1[i]);
            acc0[i] = fmaf(zv.y, wa[1], acc0[i]);
            acc1[i] = fmaf(zv.y, wb[1], acc1[i]);
            acc0[i] = fmaf(zv.z, wa[2], acc0[i]);
            acc1[i] = fmaf(zv.z, wb[2], acc1[i]);
            acc0[i] = fmaf(zv.w, wa[3], acc0[i]);
            acc1[i] = fmaf(zv.w, wb[3], acc1[i]);
        }
    }

    #pragma unroll
    for (int i = 0; i < 8; ++i) {
        int n = nbase + i;
        if (n < NN) {
            out[(size_t)n * DIM + lane]      = acc0[i];
            out[(size_t)n * DIM + lane + 64] = acc1[i];
        }
    }
}

extern "C" void kernel_launch(void* const* d_in, const int* in_sizes, int n_in,
                              void* d_out, int out_size, void* d_ws, size_t ws_size,
                              hipStream_t stream) {
    const float* h  = (const float*)d_in[0];
    const void*  ei = d_in[1];
    const float* W1 = (const float*)d_in[2];
    const float* b1 = (const float*)d_in[3];
    const float* W2 = (const float*)d_in[4];
    const float* b2 = (const float*)d_in[5];
    const float* U1 = (const float*)d_in[6];
    const float* c1 = (const float*)d_in[7];
    const float* U2 = (const float*)d_in[8];
    const float* c2 = (const float*)d_in[9];
    float* out = (float*)d_out;

    // ws layout (big path):
    //   Mh    @ 0           bf16 [NN][128]   12,800,000 B
    //   col32 @ 12,800,000  int  [EE]         3,200,000 B
    //   deg   @ 16,000,000  int  [NN]           200,000 B
    //   off   @ 16,200,000  int  [NN]           200,000 B
    //   flag  @ 16,400,000  int                      64 B
    //   W1t   @ 16,400,064  bf16 [128][128]      32,768 B
    //   W2t   @ 16,432,832  bf16 [128][128]      32,768 B
    const size_t BIG_BYTES = 16465600;
    const bool big = ws_size >= BIG_BYTES;

    char* wsb = (char*)d_ws;
    unsigned short* Mh;
    int *col32, *deg, *off, *flag;
    unsigned short *W1t, *W2t;
    if (big) {
        Mh    = (unsigned short*)wsb;
        col32 = (int*)(wsb + 12800000);
        deg   = (int*)(wsb + 16000000);
        off   = (int*)(wsb + 16200000);
        flag  = (int*)(wsb + 16400000);
        W1t   = (unsigned short*)(wsb + 16400064);
        W2t   = (unsigned short*)(wsb + 16432832);
    } else {
        Mh    = nullptr;
        col32 = nullptr;
        deg   = (int*)wsb;
        off   = (int*)(wsb + 200000);
        flag  = (int*)(wsb + 400000);
        W1t   = (unsigned short*)(wsb + 400064);
        W2t   = (unsigned short*)(wsb + 400064 + 32768);
    }

    detect_i64_kernel<<<1, 64, 0, stream>>>((const int*)ei, flag);
    prep_w_kernel<<<128, 256, 0, stream>>>(W1, W2, W1t, W2t);
    hipMemsetAsync(deg, 0, (size_t)NN * sizeof(int), stream);
    deg_i_kernel<<<(EE + 255) / 256, 256, 0, stream>>>(ei, flag, deg);

    if (big) {
        scan_kernel<<<1, 256, 0, stream>>>(deg, off);
        fill_kernel<<<(EE + 255) / 256, 256, 0, stream>>>(ei, flag, off, col32);
        node_mlp_kernel<<<(NN + 63) / 64, 256, 0, stream>>>(h, W1t, b1, W2t, b2, Mh);
        gather_reduce_kernel<<<(NN + 3) / 4, 256, 0, stream>>>(Mh, col32, off, deg, out);
    } else {
        hipMemsetAsync(d_out, 0, (size_t)NN * DIM * sizeof(float), stream);
        msg_kernel<<<EE / 64, 256, 0, stream>>>(h, ei, flag, W1t, b1, W2t, b2, out);
    }
    upd_kernel<<<(NN + 31) / 32, 256, 0, stream>>>(h, out, deg, U1, c1, U2, c2, out);
}

// Round 3
// 303.034 us; speedup vs baseline: 2.4176x; 1.0057x over previous
//
#include <hip/hip_runtime.h>
#include <cstddef>

#define NN 50000
#define EE 800000
#define DIM 128

typedef __attribute__((ext_vector_type(8))) short bf16x8;
typedef __attribute__((ext_vector_type(4))) float f32x4;

// ---------------------------------------------------------------------------
// helpers
// ---------------------------------------------------------------------------
__device__ __forceinline__ unsigned short f2bf(float x) {
    unsigned u = __float_as_uint(x);
    unsigned r = (u + 0x7FFFu + ((u >> 16) & 1u)) >> 16;   // RNE
    return (unsigned short)r;
}

__device__ __forceinline__ float bf2f(unsigned short b) {
    return __uint_as_float((unsigned)b << 16);
}

__device__ __forceinline__ int load_idx(const void* ei, bool i64, long long i) {
    return i64 ? (int)((const long long*)ei)[i] : ((const int*)ei)[i];
}

// int64-vs-int32 detection (reference declares int64; JAX x64-off emits int32)
__global__ void detect_i64_kernel(const int* __restrict__ ei, int* __restrict__ flag) {
    int l = threadIdx.x;           // 64 threads
    int v = ei[2 * l + 1];
    unsigned long long b = __ballot(v != 0);
    if (l == 0) flag[0] = (b == 0ULL) ? 1 : 0;
}

// convert W1,W2 (f32, [k][n]) -> bf16 transposed [n][k]
__global__ __launch_bounds__(256) void prep_w_kernel(
    const float* __restrict__ W1, const float* __restrict__ W2,
    unsigned short* __restrict__ W1t, unsigned short* __restrict__ W2t)
{
    int idx = blockIdx.x * 256 + threadIdx.x;     // 32768 total
    int m   = idx >> 14;
    int rem = idx & 16383;
    int n = rem >> 7, k = rem & 127;
    const float* W = m ? W2 : W1;
    unsigned short* Wt = m ? W2t : W1t;
    Wt[n * DIM + k] = f2bf(W[k * DIM + n]);
}

// convert U1 (256x128), U2 (128x128) -> transposed [n][k] split-bf16 hi/lo
__global__ __launch_bounds__(256) void prep_u_kernel(
    const float* __restrict__ U1, const float* __restrict__ U2,
    unsigned short* __restrict__ U1h, unsigned short* __restrict__ U1l,
    unsigned short* __restrict__ U2h, unsigned short* __restrict__ U2l)
{
    int idx = blockIdx.x * 256 + threadIdx.x;     // 49152 total
    float w;
    unsigned short *Hp, *Lp;
    int oi;
    if (idx < 32768) {
        int k = idx >> 7, n = idx & 127;          // U1[k][n], k in [0,256)
        w  = U1[idx];
        oi = n * 256 + k;
        Hp = U1h; Lp = U1l;
    } else {
        int r = idx - 32768;
        int k = r >> 7, n = r & 127;              // U2[k][n], k in [0,128)
        w  = U2[r];
        oi = n * 128 + k;
        Hp = U2h; Lp = U2l;
    }
    unsigned short hx = f2bf(w);
    Hp[oi] = hx;
    Lp[oi] = f2bf(w - bf2f(hx));
}

// degree count (int)
__global__ __launch_bounds__(256) void deg_i_kernel(const void* __restrict__ ei,
                                                    const int* __restrict__ flag,
                                                    int* __restrict__ deg) {
    bool i64 = flag[0] != 0;
    int e = blockIdx.x * 256 + threadIdx.x;
    if (e < EE) {
        int r = load_idx(ei, i64, e);              // row = edge_index[0][e]
        atomicAdd(&deg[r], 1);
    }
}

// exclusive prefix scan over deg[NN] -> off[NN]; single block of 256 threads.
__global__ __launch_bounds__(256) void scan_kernel(const int* __restrict__ deg,
                                                   int* __restrict__ off) {
    const int C = 196;                 // 256*196 = 50176 >= NN
    int t = threadIdx.x;
    int base = t * C;
    int sum = 0;
    if (base + C <= NN) {
        const int4* p = (const int4*)(deg + base);
        #pragma unroll 7
        for (int i = 0; i < C / 4; ++i) { int4 v = p[i]; sum += v.x + v.y + v.z + v.w; }
    } else {
        for (int i = 0; i < C; ++i) { int n = base + i; if (n < NN) sum += deg[n]; }
    }
    __shared__ int ps[256];
    ps[t] = sum;
    __syncthreads();
    for (int s = 1; s < 256; s <<= 1) {
        int v = (t >= s) ? ps[t - s] : 0;
        __syncthreads();
        ps[t] += v;
        __syncthreads();
    }
    int run = (t == 0) ? 0 : ps[t - 1];
    if (base + C <= NN) {
        const int4* dp = (const int4*)(deg + base);
        int4* op = (int4*)(off + base);
        for (int i = 0; i < C / 4; ++i) {
            int4 v = dp[i];
            int4 o;
            o.x = run; run += v.x;
            o.y = run; run += v.y;
            o.z = run; run += v.z;
            o.w = run; run += v.w;
            op[i] = o;
        }
    } else {
        for (int i = 0; i < C; ++i) {
            int n = base + i;
            if (n < NN) { off[n] = run; run += deg[n]; }
        }
    }
}

// slot claim: off[r]++ becomes segment end; col32[slot] = source node (int32)
__global__ __launch_bounds__(256) void fill_kernel(const void* __restrict__ ei,
                                                   const int* __restrict__ flag,
                                                   int* __restrict__ off,
                                                   int* __restrict__ col32) {
    bool i64 = flag[0] != 0;
    int e = blockIdx.x * 256 + threadIdx.x;
    if (e < EE) {
        int r = load_idx(ei, i64, e);
        int c = load_idx(ei, i64, (long long)EE + e);
        int slot = atomicAdd(&off[r], 1);
        col32[slot] = c;
    }
}

// ---------------------------------------------------------------------------
// Node-level message MLP: Mh[n] = relu(relu(h[n]@W1+b1)@W2+b2), bf16 out.
// 50k rows (once per node, not per edge). Wave-private LDS, no barriers.
// mfma_f32_16x16x32_bf16: A row=l&15, k=8*(l>>4)+i ; B col=l&15, same k ;
// D col=l&15, row=4*(l>>4)+j  (m89-verified).
// ---------------------------------------------------------------------------
__global__ __launch_bounds__(256) void node_mlp_kernel(
    const float* __restrict__ h,
    const unsigned short* __restrict__ W1t, const float* __restrict__ b1,
    const unsigned short* __restrict__ W2t, const float* __restrict__ b2,
    unsigned short* __restrict__ Mh)
{
    __shared__ unsigned short xs[4][16][136];   // bf16, +8 pad
    const int tid  = threadIdx.x;
    const int lane = tid & 63;
    const int wid  = tid >> 6;
    const int g    = lane >> 4;     // k-group
    const int c    = lane & 15;     // col / row-in-tile
    const int nbase = blockIdx.x * 64 + wid * 16;

    #pragma unroll
    for (int e = 0; e < 16; ++e) {
        int n = nbase + e;
        int nc = n < NN ? n : NN - 1;
        float2 v = *(const float2*)(h + (size_t)nc * DIM + lane * 2);
        unsigned p = (unsigned)f2bf(v.x) | ((unsigned)f2bf(v.y) << 16);
        *(unsigned*)&xs[wid][e][lane * 2] = p;
    }

    bf16x8 a[4];
    #pragma unroll
    for (int s = 0; s < 4; ++s)
        a[s] = *(const bf16x8*)&xs[wid][c][s * 32 + g * 8];

    f32x4 acc[8];
    #pragma unroll
    for (int t = 0; t < 8; ++t) {
        float bv = b1[t * 16 + c];
        acc[t] = (f32x4){bv, bv, bv, bv};
    }
    #pragma unroll
    for (int t = 0; t < 8; ++t) {
        #pragma unroll
        for (int s = 0; s < 4; ++s) {
            bf16x8 bf = *(const bf16x8*)&W1t[(t * 16 + c) * DIM + s * 32 + g * 8];
            acc[t] = __builtin_amdgcn_mfma_f32_16x16x32_bf16(a[s], bf, acc[t], 0, 0, 0);
        }
    }
    #pragma unroll
    for (int t = 0; t < 8; ++t)
        #pragma unroll
        for (int j = 0; j < 4; ++j)
            xs[wid][g * 4 + j][t * 16 + c] = f2bf(fmaxf(acc[t][j], 0.f));

    #pragma unroll
    for (int s = 0; s < 4; ++s)
        a[s] = *(const bf16x8*)&xs[wid][c][s * 32 + g * 8];

    #pragma unroll
    for (int t = 0; t < 8; ++t) {
        float bv = b2[t * 16 + c];
        acc[t] = (f32x4){bv, bv, bv, bv};
    }
    #pragma unroll
    for (int t = 0; t < 8; ++t) {
        #pragma unroll
        for (int s = 0; s < 4; ++s) {
            bf16x8 bf = *(const bf16x8*)&W2t[(t * 16 + c) * DIM + s * 32 + g * 8];
            acc[t] = __builtin_amdgcn_mfma_f32_16x16x32_bf16(a[s], bf, acc[t], 0, 0, 0);
        }
    }

    #pragma unroll
    for (int t = 0; t < 8; ++t)
        #pragma unroll
        for (int j = 0; j < 4; ++j)
            xs[wid][g * 4 + j][t * 16 + c] = f2bf(fmaxf(acc[t][j], 0.f));

    #pragma unroll
    for (int e = 0; e < 16; ++e) {
        int n = nbase + e;
        if (n < NN)
            *(unsigned*)(Mh + (size_t)n * DIM + lane * 2) = *(const unsigned*)&xs[wid][e][lane * 2];
    }
}

// ---------------------------------------------------------------------------
// Gather-sum: one wave per node; agg[n] = sum over its edges of Mh[col].
// Mh is 12.8 MB (L2/L3 resident). 4 gathers in flight per iteration.
// ---------------------------------------------------------------------------
__global__ __launch_bounds__(256) void gather_reduce_kernel(
    const unsigned short* __restrict__ Mh, const int* __restrict__ col32,
    const int* __restrict__ off_end, const int* __restrict__ deg,
    float* __restrict__ agg)
{
    int n = blockIdx.x * 4 + (threadIdx.x >> 6);
    int lane = threadIdx.x & 63;
    if (n >= NN) return;
    int d = deg[n];
    int end = off_end[n];
    int start = end - d;

    float a0 = 0.f, a1 = 0.f, b0 = 0.f, b1 = 0.f;
    float c0 = 0.f, c1 = 0.f, d0 = 0.f, d1 = 0.f;
    for (int base = 0; base < d; base += 64) {
        int m = d - base; if (m > 64) m = 64;
        int idx = (lane < m) ? col32[start + base + lane] : 0;
        int j = 0;
        for (; j + 4 <= m; j += 4) {
            int s0 = __shfl(idx, j);
            int s1 = __shfl(idx, j + 1);
            int s2 = __shfl(idx, j + 2);
            int s3 = __shfl(idx, j + 3);
            unsigned u0 = *(const unsigned*)(Mh + (size_t)s0 * DIM + lane * 2);
            unsigned u1 = *(const unsigned*)(Mh + (size_t)s1 * DIM + lane * 2);
            unsigned u2 = *(const unsigned*)(Mh + (size_t)s2 * DIM + lane * 2);
            unsigned u3 = *(const unsigned*)(Mh + (size_t)s3 * DIM + lane * 2);
            a0 += __uint_as_float(u0 << 16);
            a1 += __uint_as_float(u0 & 0xFFFF0000u);
            b0 += __uint_as_float(u1 << 16);
            b1 += __uint_as_float(u1 & 0xFFFF0000u);
            c0 += __uint_as_float(u2 << 16);
            c1 += __uint_as_float(u2 & 0xFFFF0000u);
            d0 += __uint_as_float(u3 << 16);
            d1 += __uint_as_float(u3 & 0xFFFF0000u);
        }
        for (; j < m; ++j) {
            int s0 = __shfl(idx, j);
            unsigned u0 = *(const unsigned*)(Mh + (size_t)s0 * DIM + lane * 2);
            a0 += __uint_as_float(u0 << 16);
            a1 += __uint_as_float(u0 & 0xFFFF0000u);
        }
    }
    float2 o;
    o.x = (a0 + b0) + (c0 + d0);
    o.y = (a1 + b1) + (c1 + d1);
    *(float2*)(agg + (size_t)n * DIM + lane * 2) = o;
}

// ---------------------------------------------------------------------------
// Update MLP via split-bf16 MFMA (hi/lo decomposition, ~1e-5 rel accuracy):
// out = relu([h, agg/deg]@U1 + c1)@U2 + c2.
// Per fp32 x: hi=bf16(x), lo=bf16(x-hi); x*w ~ hi*wh + lo*wh + hi*wl.
// Wave-private LDS, no barriers. Same fragment layout as node_mlp.
// ---------------------------------------------------------------------------
__global__ __launch_bounds__(256) void upd_mfma_kernel(
    const float* __restrict__ h, const float* __restrict__ aggout,
    const int* __restrict__ deg,
    const unsigned short* __restrict__ U1h, const unsigned short* __restrict__ U1l,
    const unsigned short* __restrict__ U2h, const unsigned short* __restrict__ U2l,
    const float* __restrict__ c1, const float* __restrict__ c2,
    float* __restrict__ out)
{
    __shared__ unsigned short xs[4][2][16][136];   // hi/lo tiles, wave-private
    const int tid  = threadIdx.x;
    const int lane = tid & 63;
    const int wid  = tid >> 6;
    const int g    = lane >> 4;
    const int c    = lane & 15;
    const int nbase = blockIdx.x * 64 + wid * 16;

    f32x4 acc[8];
    #pragma unroll
    for (int t = 0; t < 8; ++t) {
        float bv = c1[t * 16 + c];
        acc[t] = (f32x4){bv, bv, bv, bv};
    }

    // ---- layer 1: K=256 in two 128-chunks (kc=0: h, kc=1: agg/deg) ----
    #pragma unroll
    for (int kc = 0; kc < 2; ++kc) {
        #pragma unroll
        for (int e = 0; e < 16; ++e) {
            int n = nbase + e;
            int nc = n < NN ? n : NN - 1;
            float2 v;
            if (kc == 0) {
                v = *(const float2*)(h + (size_t)nc * DIM + lane * 2);
            } else {
                float inv = 1.0f / fmaxf((float)deg[nc], 1.0f);
                v = *(const float2*)(aggout + (size_t)nc * DIM + lane * 2);
                v.x *= inv; v.y *= inv;
            }
            unsigned short hx = f2bf(v.x), hy = f2bf(v.y);
            unsigned short lx = f2bf(v.x - bf2f(hx)), ly = f2bf(v.y - bf2f(hy));
            *(unsigned*)&xs[wid][0][e][lane * 2] = (unsigned)hx | ((unsigned)hy << 16);
            *(unsigned*)&xs[wid][1][e][lane * 2] = (unsigned)lx | ((unsigned)ly << 16);
        }

        bf16x8 ah[4], al[4];
        #pragma unroll
        for (int s = 0; s < 4; ++s) {
            ah[s] = *(const bf16x8*)&xs[wid][0][c][s * 32 + g * 8];
            al[s] = *(const bf16x8*)&xs[wid][1][c][s * 32 + g * 8];
        }
        #pragma unroll
        for (int t = 0; t < 8; ++t) {
            #pragma unroll
            for (int s = 0; s < 4; ++s) {
                int kof = kc * 128 + s * 32 + g * 8;
                bf16x8 bh = *(const bf16x8*)&U1h[(t * 16 + c) * 256 + kof];
                bf16x8 bl = *(const bf16x8*)&U1l[(t * 16 + c) * 256 + kof];
                acc[t] = __builtin_amdgcn_mfma_f32_16x16x32_bf16(ah[s], bh, acc[t], 0, 0, 0);
                acc[t] = __builtin_amdgcn_mfma_f32_16x16x32_bf16(al[s], bh, acc[t], 0, 0, 0);
                acc[t] = __builtin_amdgcn_mfma_f32_16x16x32_bf16(ah[s], bl, acc[t], 0, 0, 0);
            }
        }
    }

    // ---- relu + split -> LDS [row][col] ----
    #pragma unroll
    for (int t = 0; t < 8; ++t)
        #pragma unroll
        for (int j = 0; j < 4; ++j) {
            float yv = fmaxf(acc[t][j], 0.f);
            unsigned short hx = f2bf(yv);
            xs[wid][0][g * 4 + j][t * 16 + c] = hx;
            xs[wid][1][g * 4 + j][t * 16 + c] = f2bf(yv - bf2f(hx));
        }

    // ---- layer 2: K=128 ----
    bf16x8 ah[4], al[4];
    #pragma unroll
    for (int s = 0; s < 4; ++s) {
        ah[s] = *(const bf16x8*)&xs[wid][0][c][s * 32 + g * 8];
        al[s] = *(const bf16x8*)&xs[wid][1][c][s * 32 + g * 8];
    }
    f32x4 acc2[8];
    #pragma unroll
    for (int t = 0; t < 8; ++t) {
        float bv = c2[t * 16 + c];
        acc2[t] = (f32x4){bv, bv, bv, bv};
    }
    #pragma unroll
    for (int t = 0; t < 8; ++t) {
        #pragma unroll
        for (int s = 0; s < 4; ++s) {
            int kof = s * 32 + g * 8;
            bf16x8 bh = *(const bf16x8*)&U2h[(t * 16 + c) * 128 + kof];
            bf16x8 bl = *(const bf16x8*)&U2l[(t * 16 + c) * 128 + kof];
            acc2[t] = __builtin_amdgcn_mfma_f32_16x16x32_bf16(ah[s], bh, acc2[t], 0, 0, 0);
            acc2[t] = __builtin_amdgcn_mfma_f32_16x16x32_bf16(al[s], bh, acc2[t], 0, 0, 0);
            acc2[t] = __builtin_amdgcn_mfma_f32_16x16x32_bf16(ah[s], bl, acc2[t], 0, 0, 0);
        }
    }

    // ---- store: D col=c -> out col t*16+c, row 4g+j ----
    #pragma unroll
    for (int t = 0; t < 8; ++t)
        #pragma unroll
        for (int j = 0; j < 4; ++j) {
            int n = nbase + g * 4 + j;
            if (n < NN) out[(size_t)n * DIM + t * 16 + c] = acc2[t][j];
        }
}

// ---------------------------------------------------------------------------
// Fallback kernels (small workspace): atomic-scatter msg + fp32 vector upd.
// ---------------------------------------------------------------------------
__global__ __launch_bounds__(256) void msg_kernel(
    const float* __restrict__ h, const void* __restrict__ ei, const int* __restrict__ flag,
    const unsigned short* __restrict__ W1t, const float* __restrict__ b1,
    const unsigned short* __restrict__ W2t, const float* __restrict__ b2,
    float* __restrict__ agg)
{
    __shared__ unsigned short xs[4][16][136];
    const int tid  = threadIdx.x;
    const int lane = tid & 63;
    const int wid  = tid >> 6;
    const int g    = lane >> 4;
    const int c    = lane & 15;
    const bool i64 = flag[0] != 0;
    const int ebase = blockIdx.x * 64 + wid * 16;

    #pragma unroll
    for (int e = 0; e < 16; ++e) {
        int src = load_idx(ei, i64, (long long)EE + (ebase + e));
        float2 v = *(const float2*)(h + (size_t)src * DIM + lane * 2);
        unsigned p = (unsigned)f2bf(v.x) | ((unsigned)f2bf(v.y) << 16);
        *(unsigned*)&xs[wid][e][lane * 2] = p;
    }
    __syncthreads();

    bf16x8 a[4];
    #pragma unroll
    for (int s = 0; s < 4; ++s)
        a[s] = *(const bf16x8*)&xs[wid][c][s * 32 + g * 8];

    f32x4 acc[8];
    #pragma unroll
    for (int t = 0; t < 8; ++t) {
        float bv = b1[t * 16 + c];
        acc[t] = (f32x4){bv, bv, bv, bv};
    }
    #pragma unroll
    for (int t = 0; t < 8; ++t) {
        #pragma unroll
        for (int s = 0; s < 4; ++s) {
            bf16x8 bf = *(const bf16x8*)&W1t[(t * 16 + c) * DIM + s * 32 + g * 8];
            acc[t] = __builtin_amdgcn_mfma_f32_16x16x32_bf16(a[s], bf, acc[t], 0, 0, 0);
        }
    }
    __syncthreads();
    #pragma unroll
    for (int t = 0; t < 8; ++t)
        #pragma unroll
        for (int j = 0; j < 4; ++j)
            xs[wid][g * 4 + j][t * 16 + c] = f2bf(fmaxf(acc[t][j], 0.f));
    __syncthreads();

    #pragma unroll
    for (int s = 0; s < 4; ++s)
        a[s] = *(const bf16x8*)&xs[wid][c][s * 32 + g * 8];

    #pragma unroll
    for (int t = 0; t < 8; ++t) {
        float bv = b2[t * 16 + c];
        acc[t] = (f32x4){bv, bv, bv, bv};
    }
    #pragma unroll
    for (int t = 0; t < 8; ++t) {
        #pragma unroll
        for (int s = 0; s < 4; ++s) {
            bf16x8 bf = *(const bf16x8*)&W2t[(t * 16 + c) * DIM + s * 32 + g * 8];
            acc[t] = __builtin_amdgcn_mfma_f32_16x16x32_bf16(a[s], bf, acc[t], 0, 0, 0);
        }
    }

    #pragma unroll
    for (int j = 0; j < 4; ++j) {
        int r = load_idx(ei, i64, ebase + g * 4 + j);
        #pragma unroll
        for (int t = 0; t < 8; ++t)
            atomicAdd(&agg[(size_t)r * DIM + t * 16 + c], fmaxf(acc[t][j], 0.f));
    }
}

__global__ __launch_bounds__(256) void upd_kernel(
    const float* __restrict__ h, const float* __restrict__ aggout,
    const int* __restrict__ deg,
    const float* __restrict__ U1, const float* __restrict__ c1,
    const float* __restrict__ U2, const float* __restrict__ c2,
    float* __restrict__ out)
{
    __shared__ float zs[4][8][2 * DIM];   // 32 KiB
    const int tid  = threadIdx.x;
    const int lane = tid & 63;
    const int wid  = tid >> 6;
    const int nbase = blockIdx.x * 32 + wid * 8;

    #pragma unroll
    for (int i = 0; i < 8; ++i) {
        int n = nbase + i;
        if (n < NN) {
            float2 hv = *(const float2*)(h + (size_t)n * DIM + lane * 2);
            *(float2*)&zs[wid][i][lane * 2] = hv;
            float d = fmaxf((float)deg[n], 1.0f);
            float inv = 1.0f / d;
            float2 av = *(const float2*)(aggout + (size_t)n * DIM + lane * 2);
            av.x *= inv; av.y *= inv;
            *(float2*)&zs[wid][i][DIM + lane * 2] = av;
        }
    }
    __syncthreads();

    float acc0[8], acc1[8];
    {
        float cc0 = c1[lane], cc1 = c1[lane + 64];
        #pragma unroll
        for (int i = 0; i < 8; ++i) { acc0[i] = cc0; acc1[i] = cc1; }
    }
    for (int k = 0; k < 2 * DIM; k += 4) {
        float wa[4], wb[4];
        #pragma unroll
        for (int kk = 0; kk < 4; ++kk) {
            wa[kk] = U1[(k + kk) * DIM + lane];
            wb[kk] = U1[(k + kk) * DIM + lane + 64];
        }
        #pragma unroll
        for (int i = 0; i < 8; ++i) {
            float4 zv = *(const float4*)&zs[wid][i][k];
            acc0[i] = fmaf(zv.x, wa[0], acc0[i]);
            acc1[i] = fmaf(zv.x, wb[0], acc1[i]);
            acc0[i] = fmaf(zv.y, wa[1], acc0[i]);
            acc1[i] = fmaf(zv.y, wb[1], acc1[i]);
            acc0[i] = fmaf(zv.z, wa[2], acc0[i]);
            acc1[i] = fmaf(zv.z, wb[2], acc1[i]);
            acc0[i] = fmaf(zv.w, wa[3], acc0[i]);
            acc1[i] = fmaf(zv.w, wb[3], acc1[i]);
        }
    }
    __syncthreads();
    #pragma unroll
    for (int i = 0; i < 8; ++i) {
        zs[wid][i][lane]      = fmaxf(acc0[i], 0.f);
        zs[wid][i][lane + 64] = fmaxf(acc1[i], 0.f);
    }
    __syncthreads();

    {
        float cc0 = c2[lane], cc1 = c2[lane + 64];
        #pragma unroll
        for (int i = 0; i < 8; ++i) { acc0[i] = cc0; acc1[i] = cc1; }
    }
    for (int k = 0; k < DIM; k += 4) {
        float wa[4], wb[4];
        #pragma unroll
        for (int kk = 0; kk < 4; ++kk) {
            wa[kk] = U2[(k + kk) * DIM + lane];
            wb[kk] = U2[(k + kk) * DIM + lane + 64];
        }
        #pragma unroll
        for (int i = 0; i < 8; ++i) {
            float4 zv = *(const float4*)&zs[wid][i][k];
            acc0[i] = fmaf(zv.x, wa[0], acc0[i]);
            acc1[i] = fmaf(zv.x, wb[0], acc1[i]);
            acc0[i] = fmaf(zv.y, wa[1], acc0[i]);
            acc1[i] = fmaf(zv.y, wb[1], acc1[i]);
            acc0[i] = fmaf(zv.z, wa[2], acc0[i]);
            acc1[i] = fmaf(zv.z, wb[2], acc1[i]);
            acc0[i] = fmaf(zv.w, wa[3], acc0[i]);
            acc1[i] = fmaf(zv.w, wb[3], acc1[i]);
        }
    }

    #pragma unroll
    for (int i = 0; i < 8; ++i) {
        int n = nbase + i;
        if (n < NN) {
            out[(size_t)n * DIM + lane]      = acc0[i];
            out[(size_t)n * DIM + lane + 64] = acc1[i];
        }
    }
}

extern "C" void kernel_launch(void* const* d_in, const int* in_sizes, int n_in,
                              void* d_out, int out_size, void* d_ws, size_t ws_size,
                              hipStream_t stream) {
    const float* h  = (const float*)d_in[0];
    const void*  ei = d_in[1];
    const float* W1 = (const float*)d_in[2];
    const float* b1 = (const float*)d_in[3];
    const float* W2 = (const float*)d_in[4];
    const float* b2 = (const float*)d_in[5];
    const float* U1 = (const float*)d_in[6];
    const float* c1 = (const float*)d_in[7];
    const float* U2 = (const float*)d_in[8];
    const float* c2 = (const float*)d_in[9];
    float* out = (float*)d_out;

    // ws layout (big path):
    //   Mh    @ 0           bf16 [NN][128]   12,800,000 B
    //   col32 @ 12,800,000  int  [EE]         3,200,000 B
    //   deg   @ 16,000,000  int  [NN]           200,000 B
    //   off   @ 16,200,000  int  [NN]           200,000 B
    //   flag  @ 16,400,000  int                      64 B
    //   W1t   @ 16,400,064  bf16 [128][128]      32,768 B
    //   W2t   @ 16,432,832  bf16 [128][128]      32,768 B
    //   U1h   @ 16,465,600  bf16 [128][256]      65,536 B
    //   U1l   @ 16,531,136  bf16 [128][256]      65,536 B
    //   U2h   @ 16,596,672  bf16 [128][128]      32,768 B
    //   U2l   @ 16,629,440  bf16 [128][128]      32,768 B
    const size_t BIG_BYTES = 16662208;
    const bool big = ws_size >= BIG_BYTES;

    char* wsb = (char*)d_ws;
    unsigned short *Mh, *W1t, *W2t, *U1h, *U1l, *U2h, *U2l;
    int *col32, *deg, *off, *flag;
    if (big) {
        Mh    = (unsigned short*)wsb;
        col32 = (int*)(wsb + 12800000);
        deg   = (int*)(wsb + 16000000);
        off   = (int*)(wsb + 16200000);
        flag  = (int*)(wsb + 16400000);
        W1t   = (unsigned short*)(wsb + 16400064);
        W2t   = (unsigned short*)(wsb + 16432832);
        U1h   = (unsigned short*)(wsb + 16465600);
        U1l   = (unsigned short*)(wsb + 16531136);
        U2h   = (unsigned short*)(wsb + 16596672);
        U2l   = (unsigned short*)(wsb + 16629440);
    } else {
        Mh    = nullptr; col32 = nullptr;
        U1h = U1l = U2h = U2l = nullptr;
        deg   = (int*)wsb;
        off   = (int*)(wsb + 200000);
        flag  = (int*)(wsb + 400000);
        W1t   = (unsigned short*)(wsb + 400064);
        W2t   = (unsigned short*)(wsb + 400064 + 32768);
    }

    detect_i64_kernel<<<1, 64, 0, stream>>>((const int*)ei, flag);
    prep_w_kernel<<<128, 256, 0, stream>>>(W1, W2, W1t, W2t);
    hipMemsetAsync(deg, 0, (size_t)NN * sizeof(int), stream);
    deg_i_kernel<<<(EE + 255) / 256, 256, 0, stream>>>(ei, flag, deg);

    if (big) {
        prep_u_kernel<<<192, 256, 0, stream>>>(U1, U2, U1h, U1l, U2h, U2l);
        scan_kernel<<<1, 256, 0, stream>>>(deg, off);
        fill_kernel<<<(EE + 255) / 256, 256, 0, stream>>>(ei, flag, off, col32);
        node_mlp_kernel<<<(NN + 63) / 64, 256, 0, stream>>>(h, W1t, b1, W2t, b2, Mh);
        gather_reduce_kernel<<<(NN + 3) / 4, 256, 0, stream>>>(Mh, col32, off, deg, out);
        upd_mfma_kernel<<<(NN + 63) / 64, 256, 0, stream>>>(h, out, deg, U1h, U1l, U2h, U2l, c1, c2, out);
    } else {
        hipMemsetAsync(d_out, 0, (size_t)NN * DIM * sizeof(float), stream);
        msg_kernel<<<EE / 64, 256, 0, stream>>>(h, ei, flag, W1t, b1, W2t, b2, out);
        upd_kernel<<<(NN + 31) / 32, 256, 0, stream>>>(h, out, deg, U1, c1, U2, c2, out);
    }
}

// Round 4
// 295.751 us; speedup vs baseline: 2.4771x; 1.0246x over previous
//
#include <hip/hip_runtime.h>
#include <cstddef>

#define NN 50000
#define EE 800000
#define DIM 128

typedef __attribute__((ext_vector_type(8))) short bf16x8;
typedef __attribute__((ext_vector_type(4))) float f32x4;

// ---------------------------------------------------------------------------
// helpers
// ---------------------------------------------------------------------------
__device__ __forceinline__ unsigned short f2bf(float x) {
    unsigned u = __float_as_uint(x);
    unsigned r = (u + 0x7FFFu + ((u >> 16) & 1u)) >> 16;   // RNE
    return (unsigned short)r;
}

__device__ __forceinline__ float bf2f(unsigned short b) {
    return __uint_as_float((unsigned)b << 16);
}

__device__ __forceinline__ int load_idx(const void* ei, bool i64, long long i) {
    return i64 ? (int)((const long long*)ei)[i] : ((const int*)ei)[i];
}

// int64-vs-int32 detection (reference declares int64; JAX x64-off emits int32)
__global__ void detect_i64_kernel(const int* __restrict__ ei, int* __restrict__ flag) {
    int l = threadIdx.x;           // 64 threads
    int v = ei[2 * l + 1];
    unsigned long long b = __ballot(v != 0);
    if (l == 0) flag[0] = (b == 0ULL) ? 1 : 0;
}

// one kernel: W1,W2 -> bf16 [n][k]; U1,U2 -> split hi/lo bf16 [n][k]
__global__ __launch_bounds__(256) void prep_all_kernel(
    const float* __restrict__ W1, const float* __restrict__ W2,
    const float* __restrict__ U1, const float* __restrict__ U2,
    unsigned short* __restrict__ W1t, unsigned short* __restrict__ W2t,
    unsigned short* __restrict__ U1h, unsigned short* __restrict__ U1l,
    unsigned short* __restrict__ U2h, unsigned short* __restrict__ U2l)
{
    int idx = blockIdx.x * 256 + threadIdx.x;     // 81920 total
    if (idx < 32768) {
        int m   = idx >> 14;
        int rem = idx & 16383;
        int n = rem >> 7, k = rem & 127;
        const float* W = m ? W2 : W1;
        unsigned short* Wt = m ? W2t : W1t;
        Wt[n * DIM + k] = f2bf(W[k * DIM + n]);
    } else if (idx < 65536) {
        int r = idx - 32768;                      // U1: [256][128]
        int k = r >> 7, n = r & 127;
        float w = U1[r];
        unsigned short hx = f2bf(w);
        U1h[n * 256 + k] = hx;
        U1l[n * 256 + k] = f2bf(w - bf2f(hx));
    } else {
        int r = idx - 65536;                      // U2: [128][128]
        int k = r >> 7, n = r & 127;
        float w = U2[r];
        unsigned short hx = f2bf(w);
        U2h[n * 128 + k] = hx;
        U2l[n * 128 + k] = f2bf(w - bf2f(hx));
    }
}

// legacy prep for the small-workspace fallback
__global__ __launch_bounds__(256) void prep_w_kernel(
    const float* __restrict__ W1, const float* __restrict__ W2,
    unsigned short* __restrict__ W1t, unsigned short* __restrict__ W2t)
{
    int idx = blockIdx.x * 256 + threadIdx.x;     // 32768 total
    int m   = idx >> 14;
    int rem = idx & 16383;
    int n = rem >> 7, k = rem & 127;
    const float* W = m ? W2 : W1;
    unsigned short* Wt = m ? W2t : W1t;
    Wt[n * DIM + k] = f2bf(W[k * DIM + n]);
}

// degree count (int)
__global__ __launch_bounds__(256) void deg_i_kernel(const void* __restrict__ ei,
                                                    const int* __restrict__ flag,
                                                    int* __restrict__ deg) {
    bool i64 = flag[0] != 0;
    int e = blockIdx.x * 256 + threadIdx.x;
    if (e < EE) {
        int r = load_idx(ei, i64, e);              // row = edge_index[0][e]
        atomicAdd(&deg[r], 1);
    }
}

// exclusive prefix scan over deg[NN] -> off[NN]; single block of 256 threads.
__global__ __launch_bounds__(256) void scan_kernel(const int* __restrict__ deg,
                                                   int* __restrict__ off) {
    const int C = 196;                 // 256*196 = 50176 >= NN
    int t = threadIdx.x;
    int base = t * C;
    int sum = 0;
    if (base + C <= NN) {
        const int4* p = (const int4*)(deg + base);
        #pragma unroll 7
        for (int i = 0; i < C / 4; ++i) { int4 v = p[i]; sum += v.x + v.y + v.z + v.w; }
    } else {
        for (int i = 0; i < C; ++i) { int n = base + i; if (n < NN) sum += deg[n]; }
    }
    __shared__ int ps[256];
    ps[t] = sum;
    __syncthreads();
    for (int s = 1; s < 256; s <<= 1) {
        int v = (t >= s) ? ps[t - s] : 0;
        __syncthreads();
        ps[t] += v;
        __syncthreads();
    }
    int run = (t == 0) ? 0 : ps[t - 1];
    if (base + C <= NN) {
        const int4* dp = (const int4*)(deg + base);
        int4* op = (int4*)(off + base);
        for (int i = 0; i < C / 4; ++i) {
            int4 v = dp[i];
            int4 o;
            o.x = run; run += v.x;
            o.y = run; run += v.y;
            o.z = run; run += v.z;
            o.w = run; run += v.w;
            op[i] = o;
        }
    } else {
        for (int i = 0; i < C; ++i) {
            int n = base + i;
            if (n < NN) { off[n] = run; run += deg[n]; }
        }
    }
}

// slot claim: off[r]++ becomes segment end; col32[slot] = source node (int32)
__global__ __launch_bounds__(256) void fill_kernel(const void* __restrict__ ei,
                                                   const int* __restrict__ flag,
                                                   int* __restrict__ off,
                                                   int* __restrict__ col32) {
    bool i64 = flag[0] != 0;
    int e = blockIdx.x * 256 + threadIdx.x;
    if (e < EE) {
        int r = load_idx(ei, i64, e);
        int c = load_idx(ei, i64, (long long)EE + e);
        int slot = atomicAdd(&off[r], 1);
        col32[slot] = c;
    }
}

// ---------------------------------------------------------------------------
// Node-level message MLP: Mh[n] = relu(relu(h[n]@W1+b1)@W2+b2), bf16 out.
// 50k rows (once per node, not per edge). Wave-private LDS, no barriers.
// mfma_f32_16x16x32_bf16: A row=l&15, k=8*(l>>4)+i ; B col=l&15, same k ;
// D col=l&15, row=4*(l>>4)+j  (m89-verified).
// ---------------------------------------------------------------------------
__global__ __launch_bounds__(256) void node_mlp_kernel(
    const float* __restrict__ h,
    const unsigned short* __restrict__ W1t, const float* __restrict__ b1,
    const unsigned short* __restrict__ W2t, const float* __restrict__ b2,
    unsigned short* __restrict__ Mh)
{
    __shared__ unsigned short xs[4][16][136];   // bf16, +8 pad
    const int tid  = threadIdx.x;
    const int lane = tid & 63;
    const int wid  = tid >> 6;
    const int g    = lane >> 4;     // k-group
    const int c    = lane & 15;     // col / row-in-tile
    const int half = lane >> 5;
    const int hl   = lane & 31;
    const int nbase = blockIdx.x * 64 + wid * 16;

    // float4 row staging: lanes 0-31 row e, lanes 32-63 row e+1 (16B/lane)
    #pragma unroll
    for (int e = 0; e < 16; e += 2) {
        int n = nbase + e + half;
        int nc = n < NN ? n : NN - 1;
        float4 v = *(const float4*)(h + (size_t)nc * DIM + hl * 4);
        unsigned short h0 = f2bf(v.x), h1 = f2bf(v.y), h2 = f2bf(v.z), h3 = f2bf(v.w);
        *(uint2*)&xs[wid][e + half][hl * 4] =
            (uint2){(unsigned)h0 | ((unsigned)h1 << 16), (unsigned)h2 | ((unsigned)h3 << 16)};
    }

    bf16x8 a[4];
    #pragma unroll
    for (int s = 0; s < 4; ++s)
        a[s] = *(const bf16x8*)&xs[wid][c][s * 32 + g * 8];

    f32x4 acc[8];
    #pragma unroll
    for (int t = 0; t < 8; ++t) {
        float bv = b1[t * 16 + c];
        acc[t] = (f32x4){bv, bv, bv, bv};
    }
    #pragma unroll
    for (int t = 0; t < 8; ++t) {
        #pragma unroll
        for (int s = 0; s < 4; ++s) {
            bf16x8 bf = *(const bf16x8*)&W1t[(t * 16 + c) * DIM + s * 32 + g * 8];
            acc[t] = __builtin_amdgcn_mfma_f32_16x16x32_bf16(a[s], bf, acc[t], 0, 0, 0);
        }
    }
    #pragma unroll
    for (int t = 0; t < 8; ++t)
        #pragma unroll
        for (int j = 0; j < 4; ++j)
            xs[wid][g * 4 + j][t * 16 + c] = f2bf(fmaxf(acc[t][j], 0.f));

    #pragma unroll
    for (int s = 0; s < 4; ++s)
        a[s] = *(const bf16x8*)&xs[wid][c][s * 32 + g * 8];

    #pragma unroll
    for (int t = 0; t < 8; ++t) {
        float bv = b2[t * 16 + c];
        acc[t] = (f32x4){bv, bv, bv, bv};
    }
    #pragma unroll
    for (int t = 0; t < 8; ++t) {
        #pragma unroll
        for (int s = 0; s < 4; ++s) {
            bf16x8 bf = *(const bf16x8*)&W2t[(t * 16 + c) * DIM + s * 32 + g * 8];
            acc[t] = __builtin_amdgcn_mfma_f32_16x16x32_bf16(a[s], bf, acc[t], 0, 0, 0);
        }
    }

    #pragma unroll
    for (int t = 0; t < 8; ++t)
        #pragma unroll
        for (int j = 0; j < 4; ++j)
            xs[wid][g * 4 + j][t * 16 + c] = f2bf(fmaxf(acc[t][j], 0.f));

    #pragma unroll
    for (int e = 0; e < 16; ++e) {
        int n = nbase + e;
        if (n < NN)
            *(unsigned*)(Mh + (size_t)n * DIM + lane * 2) = *(const unsigned*)&xs[wid][e][lane * 2];
    }
}

// ---------------------------------------------------------------------------
// FUSED gather + update MLP.
// Phase 1 (gather): half-wave per node (lanes 0-31 node e, 32-63 node e+1),
//   uint2 (8B) loads, 8-deep bursts -> 4KB in flight per wave; fp32 sums,
//   scale by 1/deg, hi/lo split straight into the LDS A-tile.
// Phase 2 (MLP): layer1 = agg-chunk (U1 k=128..255) + h-chunk (k=0..127),
//   split-bf16 triple-MFMA; relu; layer2 @U2; store out.
// Wave-private LDS tile [2][16][136], no barriers anywhere.
// ---------------------------------------------------------------------------
__global__ __launch_bounds__(256) void gup_kernel(
    const float* __restrict__ h,
    const unsigned short* __restrict__ Mh, const int* __restrict__ col32,
    const int* __restrict__ off_end, const int* __restrict__ deg,
    const unsigned short* __restrict__ U1h, const unsigned short* __restrict__ U1l,
    const unsigned short* __restrict__ U2h, const unsigned short* __restrict__ U2l,
    const float* __restrict__ c1, const float* __restrict__ c2,
    float* __restrict__ out)
{
    __shared__ unsigned short xs[4][2][16][136];   // hi/lo tiles, wave-private
    const int tid  = threadIdx.x;
    const int lane = tid & 63;
    const int wid  = tid >> 6;
    const int g    = lane >> 4;
    const int c    = lane & 15;
    const int half = lane >> 5;
    const int hl   = lane & 31;
    const int nbase = blockIdx.x * 64 + wid * 16;

    // ---- phase 1: gather agg rows, two nodes per pass (one per half-wave) ----
    #pragma unroll 1
    for (int e = 0; e < 16; e += 2) {
        int n = nbase + e + half;
        int nc = n < NN ? n : NN - 1;
        int d = (n < NN) ? deg[nc] : 0;
        int end = off_end[nc];
        int start = end - d;
        float s0 = 0.f, s1 = 0.f, s2 = 0.f, s3 = 0.f;
        for (int base = 0; base < d; base += 32) {
            int m = d - base; if (m > 32) m = 32;
            int idx = (hl < m) ? col32[start + base + hl] : 0;
            int j = 0;
            for (; j + 8 <= m; j += 8) {
                uint2 u[8];
                #pragma unroll
                for (int k = 0; k < 8; ++k) {
                    int si = __shfl(idx, (half << 5) + j + k);
                    u[k] = *(const uint2*)(Mh + (size_t)si * DIM + hl * 4);
                }
                #pragma unroll
                for (int k = 0; k < 8; ++k) {
                    s0 += __uint_as_float(u[k].x << 16);
                    s1 += __uint_as_float(u[k].x & 0xFFFF0000u);
                    s2 += __uint_as_float(u[k].y << 16);
                    s3 += __uint_as_float(u[k].y & 0xFFFF0000u);
                }
            }
            for (; j < m; ++j) {
                int si = __shfl(idx, (half << 5) + j);
                uint2 u0 = *(const uint2*)(Mh + (size_t)si * DIM + hl * 4);
                s0 += __uint_as_float(u0.x << 16);
                s1 += __uint_as_float(u0.x & 0xFFFF0000u);
                s2 += __uint_as_float(u0.y << 16);
                s3 += __uint_as_float(u0.y & 0xFFFF0000u);
            }
        }
        float inv = 1.0f / fmaxf((float)d, 1.0f);
        s0 *= inv; s1 *= inv; s2 *= inv; s3 *= inv;
        unsigned short h0 = f2bf(s0), h1 = f2bf(s1), h2 = f2bf(s2), h3 = f2bf(s3);
        unsigned short l0 = f2bf(s0 - bf2f(h0)), l1 = f2bf(s1 - bf2f(h1));
        unsigned short l2 = f2bf(s2 - bf2f(h2)), l3 = f2bf(s3 - bf2f(h3));
        *(uint2*)&xs[wid][0][e + half][hl * 4] =
            (uint2){(unsigned)h0 | ((unsigned)h1 << 16), (unsigned)h2 | ((unsigned)h3 << 16)};
        *(uint2*)&xs[wid][1][e + half][hl * 4] =
            (uint2){(unsigned)l0 | ((unsigned)l1 << 16), (unsigned)l2 | ((unsigned)l3 << 16)};
    }

    // ---- phase 2a: layer1, agg chunk (U1 rows 128..255) ----
    f32x4 acc[8];
    #pragma unroll
    for (int t = 0; t < 8; ++t) {
        float bv = c1[t * 16 + c];
        acc[t] = (f32x4){bv, bv, bv, bv};
    }
    {
        bf16x8 ah[4], al[4];
        #pragma unroll
        for (int s = 0; s < 4; ++s) {
            ah[s] = *(const bf16x8*)&xs[wid][0][c][s * 32 + g * 8];
            al[s] = *(const bf16x8*)&xs[wid][1][c][s * 32 + g * 8];
        }
        #pragma unroll
        for (int t = 0; t < 8; ++t) {
            #pragma unroll
            for (int s = 0; s < 4; ++s) {
                int kof = 128 + s * 32 + g * 8;
                bf16x8 bh = *(const bf16x8*)&U1h[(t * 16 + c) * 256 + kof];
                bf16x8 bl = *(const bf16x8*)&U1l[(t * 16 + c) * 256 + kof];
                acc[t] = __builtin_amdgcn_mfma_f32_16x16x32_bf16(ah[s], bh, acc[t], 0, 0, 0);
                acc[t] = __builtin_amdgcn_mfma_f32_16x16x32_bf16(al[s], bh, acc[t], 0, 0, 0);
                acc[t] = __builtin_amdgcn_mfma_f32_16x16x32_bf16(ah[s], bl, acc[t], 0, 0, 0);
            }
        }
    }

    // ---- phase 2b: layer1, h chunk (U1 rows 0..127); reuse the LDS tile ----
    #pragma unroll
    for (int e = 0; e < 16; e += 2) {
        int n = nbase + e + half;
        int nc = n < NN ? n : NN - 1;
        float4 v = *(const float4*)(h + (size_t)nc * DIM + hl * 4);
        unsigned short h0 = f2bf(v.x), h1 = f2bf(v.y), h2 = f2bf(v.z), h3 = f2bf(v.w);
        unsigned short l0 = f2bf(v.x - bf2f(h0)), l1 = f2bf(v.y - bf2f(h1));
        unsigned short l2 = f2bf(v.z - bf2f(h2)), l3 = f2bf(v.w - bf2f(h3));
        *(uint2*)&xs[wid][0][e + half][hl * 4] =
            (uint2){(unsigned)h0 | ((unsigned)h1 << 16), (unsigned)h2 | ((unsigned)h3 << 16)};
        *(uint2*)&xs[wid][1][e + half][hl * 4] =
            (uint2){(unsigned)l0 | ((unsigned)l1 << 16), (unsigned)l2 | ((unsigned)l3 << 16)};
    }
    {
        bf16x8 ah[4], al[4];
        #pragma unroll
        for (int s = 0; s < 4; ++s) {
            ah[s] = *(const bf16x8*)&xs[wid][0][c][s * 32 + g * 8];
            al[s] = *(const bf16x8*)&xs[wid][1][c][s * 32 + g * 8];
        }
        #pragma unroll
        for (int t = 0; t < 8; ++t) {
            #pragma unroll
            for (int s = 0; s < 4; ++s) {
                int kof = s * 32 + g * 8;
                bf16x8 bh = *(const bf16x8*)&U1h[(t * 16 + c) * 256 + kof];
                bf16x8 bl = *(const bf16x8*)&U1l[(t * 16 + c) * 256 + kof];
                acc[t] = __builtin_amdgcn_mfma_f32_16x16x32_bf16(ah[s], bh, acc[t], 0, 0, 0);
                acc[t] = __builtin_amdgcn_mfma_f32_16x16x32_bf16(al[s], bh, acc[t], 0, 0, 0);
                acc[t] = __builtin_amdgcn_mfma_f32_16x16x32_bf16(ah[s], bl, acc[t], 0, 0, 0);
            }
        }
    }

    // ---- relu + split -> LDS [row][col] ----
    #pragma unroll
    for (int t = 0; t < 8; ++t)
        #pragma unroll
        for (int j = 0; j < 4; ++j) {
            float yv = fmaxf(acc[t][j], 0.f);
            unsigned short hx = f2bf(yv);
            xs[wid][0][g * 4 + j][t * 16 + c] = hx;
            xs[wid][1][g * 4 + j][t * 16 + c] = f2bf(yv - bf2f(hx));
        }

    // ---- layer 2: K=128 ----
    bf16x8 ah[4], al[4];
    #pragma unroll
    for (int s = 0; s < 4; ++s) {
        ah[s] = *(const bf16x8*)&xs[wid][0][c][s * 32 + g * 8];
        al[s] = *(const bf16x8*)&xs[wid][1][c][s * 32 + g * 8];
    }
    f32x4 acc2[8];
    #pragma unroll
    for (int t = 0; t < 8; ++t) {
        float bv = c2[t * 16 + c];
        acc2[t] = (f32x4){bv, bv, bv, bv};
    }
    #pragma unroll
    for (int t = 0; t < 8; ++t) {
        #pragma unroll
        for (int s = 0; s < 4; ++s) {
            int kof = s * 32 + g * 8;
            bf16x8 bh = *(const bf16x8*)&U2h[(t * 16 + c) * 128 + kof];
            bf16x8 bl = *(const bf16x8*)&U2l[(t * 16 + c) * 128 + kof];
            acc2[t] = __builtin_amdgcn_mfma_f32_16x16x32_bf16(ah[s], bh, acc2[t], 0, 0, 0);
            acc2[t] = __builtin_amdgcn_mfma_f32_16x16x32_bf16(al[s], bh, acc2[t], 0, 0, 0);
            acc2[t] = __builtin_amdgcn_mfma_f32_16x16x32_bf16(ah[s], bl, acc2[t], 0, 0, 0);
        }
    }

    // ---- store: D col=c -> out col t*16+c, row 4g+j ----
    #pragma unroll
    for (int t = 0; t < 8; ++t)
        #pragma unroll
        for (int j = 0; j < 4; ++j) {
            int n = nbase + g * 4 + j;
            if (n < NN) out[(size_t)n * DIM + t * 16 + c] = acc2[t][j];
        }
}

// ---------------------------------------------------------------------------
// Fallback kernels (small workspace): atomic-scatter msg + fp32 vector upd.
// ---------------------------------------------------------------------------
__global__ __launch_bounds__(256) void msg_kernel(
    const float* __restrict__ h, const void* __restrict__ ei, const int* __restrict__ flag,
    const unsigned short* __restrict__ W1t, const float* __restrict__ b1,
    const unsigned short* __restrict__ W2t, const float* __restrict__ b2,
    float* __restrict__ agg)
{
    __shared__ unsigned short xs[4][16][136];
    const int tid  = threadIdx.x;
    const int lane = tid & 63;
    const int wid  = tid >> 6;
    const int g    = lane >> 4;
    const int c    = lane & 15;
    const bool i64 = flag[0] != 0;
    const int ebase = blockIdx.x * 64 + wid * 16;

    #pragma unroll
    for (int e = 0; e < 16; ++e) {
        int src = load_idx(ei, i64, (long long)EE + (ebase + e));
        float2 v = *(const float2*)(h + (size_t)src * DIM + lane * 2);
        unsigned p = (unsigned)f2bf(v.x) | ((unsigned)f2bf(v.y) << 16);
        *(unsigned*)&xs[wid][e][lane * 2] = p;
    }
    __syncthreads();

    bf16x8 a[4];
    #pragma unroll
    for (int s = 0; s < 4; ++s)
        a[s] = *(const bf16x8*)&xs[wid][c][s * 32 + g * 8];

    f32x4 acc[8];
    #pragma unroll
    for (int t = 0; t < 8; ++t) {
        float bv = b1[t * 16 + c];
        acc[t] = (f32x4){bv, bv, bv, bv};
    }
    #pragma unroll
    for (int t = 0; t < 8; ++t) {
        #pragma unroll
        for (int s = 0; s < 4; ++s) {
            bf16x8 bf = *(const bf16x8*)&W1t[(t * 16 + c) * DIM + s * 32 + g * 8];
            acc[t] = __builtin_amdgcn_mfma_f32_16x16x32_bf16(a[s], bf, acc[t], 0, 0, 0);
        }
    }
    __syncthreads();
    #pragma unroll
    for (int t = 0; t < 8; ++t)
        #pragma unroll
        for (int j = 0; j < 4; ++j)
            xs[wid][g * 4 + j][t * 16 + c] = f2bf(fmaxf(acc[t][j], 0.f));
    __syncthreads();

    #pragma unroll
    for (int s = 0; s < 4; ++s)
        a[s] = *(const bf16x8*)&xs[wid][c][s * 32 + g * 8];

    #pragma unroll
    for (int t = 0; t < 8; ++t) {
        float bv = b2[t * 16 + c];
        acc[t] = (f32x4){bv, bv, bv, bv};
    }
    #pragma unroll
    for (int t = 0; t < 8; ++t) {
        #pragma unroll
        for (int s = 0; s < 4; ++s) {
            bf16x8 bf = *(const bf16x8*)&W2t[(t * 16 + c) * DIM + s * 32 + g * 8];
            acc[t] = __builtin_amdgcn_mfma_f32_16x16x32_bf16(a[s], bf, acc[t], 0, 0, 0);
        }
    }

    #pragma unroll
    for (int j = 0; j < 4; ++j) {
        int r = load_idx(ei, i64, ebase + g * 4 + j);
        #pragma unroll
        for (int t = 0; t < 8; ++t)
            atomicAdd(&agg[(size_t)r * DIM + t * 16 + c], fmaxf(acc[t][j], 0.f));
    }
}

__global__ __launch_bounds__(256) void upd_kernel(
    const float* __restrict__ h, const float* __restrict__ aggout,
    const int* __restrict__ deg,
    const float* __restrict__ U1, const float* __restrict__ c1,
    const float* __restrict__ U2, const float* __restrict__ c2,
    float* __restrict__ out)
{
    __shared__ float zs[4][8][2 * DIM];   // 32 KiB
    const int tid  = threadIdx.x;
    const int lane = tid & 63;
    const int wid  = tid >> 6;
    const int nbase = blockIdx.x * 32 + wid * 8;

    #pragma unroll
    for (int i = 0; i < 8; ++i) {
        int n = nbase + i;
        if (n < NN) {
            float2 hv = *(const float2*)(h + (size_t)n * DIM + lane * 2);
            *(float2*)&zs[wid][i][lane * 2] = hv;
            float d = fmaxf((float)deg[n], 1.0f);
            float inv = 1.0f / d;
            float2 av = *(const float2*)(aggout + (size_t)n * DIM + lane * 2);
            av.x *= inv; av.y *= inv;
            *(float2*)&zs[wid][i][DIM + lane * 2] = av;
        }
    }
    __syncthreads();

    float acc0[8], acc1[8];
    {
        float cc0 = c1[lane], cc1 = c1[lane + 64];
        #pragma unroll
        for (int i = 0; i < 8; ++i) { acc0[i] = cc0; acc1[i] = cc1; }
    }
    for (int k = 0; k < 2 * DIM; k += 4) {
        float wa[4], wb[4];
        #pragma unroll
        for (int kk = 0; kk < 4; ++kk) {
            wa[kk] = U1[(k + kk) * DIM + lane];
            wb[kk] = U1[(k + kk) * DIM + lane + 64];
        }
        #pragma unroll
        for (int i = 0; i < 8; ++i) {
            float4 zv = *(const float4*)&zs[wid][i][k];
            acc0[i] = fmaf(zv.x, wa[0], acc0[i]);
            acc1[i] = fmaf(zv.x, wb[0], acc1[i]);
            acc0[i] = fmaf(zv.y, wa[1], acc0[i]);
            acc1[i] = fmaf(zv.y, wb[1], acc1[i]);
            acc0[i] = fmaf(zv.z, wa[2], acc0[i]);
            acc1[i] = fmaf(zv.z, wb[2], acc1[i]);
            acc0[i] = fmaf(zv.w, wa[3], acc0[i]);
            acc1[i] = fmaf(zv.w, wb[3], acc1[i]);
        }
    }
    __syncthreads();
    #pragma unroll
    for (int i = 0; i < 8; ++i) {
        zs[wid][i][lane]      = fmaxf(acc0[i], 0.f);
        zs[wid][i][lane + 64] = fmaxf(acc1[i], 0.f);
    }
    __syncthreads();

    {
        float cc0 = c2[lane], cc1 = c2[lane + 64];
        #pragma unroll
        for (int i = 0; i < 8; ++i) { acc0[i] = cc0; acc1[i] = cc1; }
    }
    for (int k = 0; k < DIM; k += 4) {
        float wa[4], wb[4];
        #pragma unroll
        for (int kk = 0; kk < 4; ++kk) {
            wa[kk] = U2[(k + kk) * DIM + lane];
            wb[kk] = U2[(k + kk) * DIM + lane + 64];
        }
        #pragma unroll
        for (int i = 0; i < 8; ++i) {
            float4 zv = *(const float4*)&zs[wid][i][k];
            acc0[i] = fmaf(zv.x, wa[0], acc0[i]);
            acc1[i] = fmaf(zv.x, wb[0], acc1[i]);
            acc0[i] = fmaf(zv.y, wa[1], acc0[i]);
            acc1[i] = fmaf(zv.y, wb[1], acc1[i]);
            acc0[i] = fmaf(zv.z, wa[2], acc0[i]);
            acc1[i] = fmaf(zv.z, wb[2], acc1[i]);
            acc0[i] = fmaf(zv.w, wa[3], acc0[i]);
            acc1[i] = fmaf(zv.w, wb[3], acc1[i]);
        }
    }

    #pragma unroll
    for (int i = 0; i < 8; ++i) {
        int n = nbase + i;
        if (n < NN) {
            out[(size_t)n * DIM + lane]      = acc0[i];
            out[(size_t)n * DIM + lane + 64] = acc1[i];
        }
    }
}

extern "C" void kernel_launch(void* const* d_in, const int* in_sizes, int n_in,
                              void* d_out, int out_size, void* d_ws, size_t ws_size,
                              hipStream_t stream) {
    const float* h  = (const float*)d_in[0];
    const void*  ei = d_in[1];
    const float* W1 = (const float*)d_in[2];
    const float* b1 = (const float*)d_in[3];
    const float* W2 = (const float*)d_in[4];
    const float* b2 = (const float*)d_in[5];
    const float* U1 = (const float*)d_in[6];
    const float* c1 = (const float*)d_in[7];
    const float* U2 = (const float*)d_in[8];
    const float* c2 = (const float*)d_in[9];
    float* out = (float*)d_out;

    // ws layout (big path):
    //   Mh    @ 0           bf16 [NN][128]   12,800,000 B
    //   col32 @ 12,800,000  int  [EE]         3,200,000 B
    //   deg   @ 16,000,000  int  [NN]           200,000 B
    //   off   @ 16,200,000  int  [NN]           200,000 B
    //   flag  @ 16,400,000  int                      64 B
    //   W1t   @ 16,400,064  bf16 [128][128]      32,768 B
    //   W2t   @ 16,432,832  bf16 [128][128]      32,768 B
    //   U1h   @ 16,465,600  bf16 [128][256]      65,536 B
    //   U1l   @ 16,531,136  bf16 [128][256]      65,536 B
    //   U2h   @ 16,596,672  bf16 [128][128]      32,768 B
    //   U2l   @ 16,629,440  bf16 [128][128]      32,768 B
    const size_t BIG_BYTES = 16662208;
    const bool big = ws_size >= BIG_BYTES;

    char* wsb = (char*)d_ws;
    unsigned short *Mh, *W1t, *W2t, *U1h, *U1l, *U2h, *U2l;
    int *col32, *deg, *off, *flag;
    if (big) {
        Mh    = (unsigned short*)wsb;
        col32 = (int*)(wsb + 12800000);
        deg   = (int*)(wsb + 16000000);
        off   = (int*)(wsb + 16200000);
        flag  = (int*)(wsb + 16400000);
        W1t   = (unsigned short*)(wsb + 16400064);
        W2t   = (unsigned short*)(wsb + 16432832);
        U1h   = (unsigned short*)(wsb + 16465600);
        U1l   = (unsigned short*)(wsb + 16531136);
        U2h   = (unsigned short*)(wsb + 16596672);
        U2l   = (unsigned short*)(wsb + 16629440);
    } else {
        Mh    = nullptr; col32 = nullptr;
        U1h = U1l = U2h = U2l = nullptr;
        deg   = (int*)wsb;
        off   = (int*)(wsb + 200000);
        flag  = (int*)(wsb + 400000);
        W1t   = (unsigned short*)(wsb + 400064);
        W2t   = (unsigned short*)(wsb + 400064 + 32768);
    }

    detect_i64_kernel<<<1, 64, 0, stream>>>((const int*)ei, flag);
    hipMemsetAsync(deg, 0, (size_t)NN * sizeof(int), stream);

    if (big) {
        prep_all_kernel<<<320, 256, 0, stream>>>(W1, W2, U1, U2, W1t, W2t, U1h, U1l, U2h, U2l);
        deg_i_kernel<<<(EE + 255) / 256, 256, 0, stream>>>(ei, flag, deg);
        scan_kernel<<<1, 256, 0, stream>>>(deg, off);
        fill_kernel<<<(EE + 255) / 256, 256, 0, stream>>>(ei, flag, off, col32);
        node_mlp_kernel<<<(NN + 63) / 64, 256, 0, stream>>>(h, W1t, b1, W2t, b2, Mh);
        gup_kernel<<<(NN + 63) / 64, 256, 0, stream>>>(h, Mh, col32, off, deg,
                                                       U1h, U1l, U2h, U2l, c1, c2, out);
    } else {
        prep_w_kernel<<<128, 256, 0, stream>>>(W1, W2, W1t, W2t);
        deg_i_kernel<<<(EE + 255) / 256, 256, 0, stream>>>(ei, flag, deg);
        hipMemsetAsync(d_out, 0, (size_t)NN * DIM * sizeof(float), stream);
        msg_kernel<<<EE / 64, 256, 0, stream>>>(h, ei, flag, W1t, b1, W2t, b2, out);
        upd_kernel<<<(NN + 31) / 32, 256, 0, stream>>>(h, out, deg, U1, c1, U2, c2, out);
    }
}

// Round 5
// 288.343 us; speedup vs baseline: 2.5407x; 1.0257x over previous
//
#include <hip/hip_runtime.h>
#include <cstddef>

#define NN 50000
#define EE 800000
#define DIM 128

#define PREP_BLKS 320
#define ZERO_BLKS 49
#define FILL_BLKS 3125
#define MLP_BLKS  782   // ceil(NN/64)

typedef __attribute__((ext_vector_type(8))) short bf16x8;
typedef __attribute__((ext_vector_type(4))) float f32x4;

// ---------------------------------------------------------------------------
// helpers
// ---------------------------------------------------------------------------
__device__ __forceinline__ unsigned short f2bf(float x) {
    unsigned u = __float_as_uint(x);
    unsigned r = (u + 0x7FFFu + ((u >> 16) & 1u)) >> 16;   // RNE
    return (unsigned short)r;
}

__device__ __forceinline__ float bf2f(unsigned short b) {
    return __uint_as_float((unsigned)b << 16);
}

__device__ __forceinline__ int load_idx(const void* ei, bool i64, long long i) {
    return i64 ? (int)((const long long*)ei)[i] : ((const int*)ei)[i];
}

// per-wave i64 detection: identical ballot to the old detect kernel
// (reads ei[2l+1], l=0..63; all-zero high words => int64)
__device__ __forceinline__ bool detect_i64_inline(const void* ei) {
    int l = threadIdx.x & 63;
    int v = ((const int*)ei)[2 * l + 1];
    return __ballot(v != 0) == 0ULL;
}

// ---------------------------------------------------------------------------
// L0: weight prep (W bf16-T; U split hi/lo bf16-T) + deg zeroing, one launch
// ---------------------------------------------------------------------------
__global__ __launch_bounds__(256) void prep_zero_kernel(
    const float* __restrict__ W1, const float* __restrict__ W2,
    const float* __restrict__ U1, const float* __restrict__ U2,
    unsigned short* __restrict__ W1t, unsigned short* __restrict__ W2t,
    unsigned short* __restrict__ U1h, unsigned short* __restrict__ U1l,
    unsigned short* __restrict__ U2h, unsigned short* __restrict__ U2l,
    int* __restrict__ deg)
{
    int bid = blockIdx.x;
    if (bid < PREP_BLKS) {
        int idx = bid * 256 + threadIdx.x;     // 81920 total
        if (idx < 32768) {
            int m   = idx >> 14;
            int rem = idx & 16383;
            int n = rem >> 7, k = rem & 127;
            const float* W = m ? W2 : W1;
            unsigned short* Wt = m ? W2t : W1t;
            Wt[n * DIM + k] = f2bf(W[k * DIM + n]);
        } else if (idx < 65536) {
            int r = idx - 32768;                      // U1: [256][128]
            int k = r >> 7, n = r & 127;
            float w = U1[r];
            unsigned short hx = f2bf(w);
            U1h[n * 256 + k] = hx;
            U1l[n * 256 + k] = f2bf(w - bf2f(hx));
        } else {
            int r = idx - 65536;                      // U2: [128][128]
            int k = r >> 7, n = r & 127;
            float w = U2[r];
            unsigned short hx = f2bf(w);
            U2h[n * 128 + k] = hx;
            U2l[n * 128 + k] = f2bf(w - bf2f(hx));
        }
    } else {
        int base = (bid - PREP_BLKS) * 1024 + threadIdx.x * 4;
        if (base + 4 <= NN) {
            *(int4*)(deg + base) = (int4){0, 0, 0, 0};
        } else {
            #pragma unroll
            for (int k = 0; k < 4; ++k)
                if (base + k < NN) deg[base + k] = 0;
        }
    }
}

// ---------------------------------------------------------------------------
// L1: degree count (inline i64 detect)
// ---------------------------------------------------------------------------
__global__ __launch_bounds__(256) void deg_fast_kernel(const void* __restrict__ ei,
                                                       int* __restrict__ deg) {
    bool i64 = detect_i64_inline(ei);
    int e = blockIdx.x * 256 + threadIdx.x;
    if (e < EE) {
        int r = load_idx(ei, i64, e);
        atomicAdd(&deg[r], 1);
    }
}

// ---------------------------------------------------------------------------
// L2: exclusive prefix scan, single block of 1024 threads, int4-vectorized
// ---------------------------------------------------------------------------
__global__ __launch_bounds__(1024) void scan_kernel(const int* __restrict__ deg,
                                                    int* __restrict__ off) {
    const int C = 52;                 // 1024*52 = 53248 >= NN
    int t = threadIdx.x;
    int base = t * C;
    int sum = 0;
    if (base + C <= NN) {
        const int4* p = (const int4*)(deg + base);
        #pragma unroll 13
        for (int i = 0; i < C / 4; ++i) { int4 v = p[i]; sum += v.x + v.y + v.z + v.w; }
    } else {
        for (int i = 0; i < C; ++i) { int n = base + i; if (n < NN) sum += deg[n]; }
    }
    __shared__ int ps[1024];
    ps[t] = sum;
    __syncthreads();
    for (int s = 1; s < 1024; s <<= 1) {
        int v = (t >= s) ? ps[t - s] : 0;
        __syncthreads();
        ps[t] += v;
        __syncthreads();
    }
    int run = (t == 0) ? 0 : ps[t - 1];
    if (base + C <= NN) {
        const int4* dp = (const int4*)(deg + base);
        int4* op = (int4*)(off + base);
        for (int i = 0; i < C / 4; ++i) {
            int4 v = dp[i];
            int4 o;
            o.x = run; run += v.x;
            o.y = run; run += v.y;
            o.z = run; run += v.z;
            o.w = run; run += v.w;
            op[i] = o;
        }
    } else {
        for (int i = 0; i < C; ++i) {
            int n = base + i;
            if (n < NN) { off[n] = run; run += deg[n]; }
        }
    }
}

// ---------------------------------------------------------------------------
// L3: fill (CSR slot claim) + node-level message MLP, one launch.
// Blocks [0,FILL_BLKS): per-edge slot claim; off[r]++ becomes segment end.
// Blocks [FILL_BLKS, FILL_BLKS+MLP_BLKS): Mh[n] = relu(relu(h@W1+b1)@W2+b2).
// ---------------------------------------------------------------------------
__global__ __launch_bounds__(256) void fill_mlp_kernel(
    const void* __restrict__ ei, const float* __restrict__ h,
    const unsigned short* __restrict__ W1t, const float* __restrict__ b1,
    const unsigned short* __restrict__ W2t, const float* __restrict__ b2,
    int* __restrict__ off, int* __restrict__ col32,
    unsigned short* __restrict__ Mh)
{
    __shared__ unsigned short xs[4][16][136];   // bf16, +8 pad (mlp part only)

    if (blockIdx.x < FILL_BLKS) {
        bool i64 = detect_i64_inline(ei);
        int e = blockIdx.x * 256 + threadIdx.x;
        if (e < EE) {
            int r = load_idx(ei, i64, e);
            int c = load_idx(ei, i64, (long long)EE + e);
            int slot = atomicAdd(&off[r], 1);
            col32[slot] = c;
        }
        return;
    }

    const int tid  = threadIdx.x;
    const int lane = tid & 63;
    const int wid  = tid >> 6;
    const int g    = lane >> 4;     // k-group
    const int c    = lane & 15;     // col / row-in-tile
    const int half = lane >> 5;
    const int hl   = lane & 31;
    const int nbase = (blockIdx.x - FILL_BLKS) * 64 + wid * 16;

    // float4 row staging: lanes 0-31 row e, lanes 32-63 row e+1 (16B/lane)
    #pragma unroll
    for (int e = 0; e < 16; e += 2) {
        int n = nbase + e + half;
        int nc = n < NN ? n : NN - 1;
        float4 v = *(const float4*)(h + (size_t)nc * DIM + hl * 4);
        unsigned short h0 = f2bf(v.x), h1 = f2bf(v.y), h2 = f2bf(v.z), h3 = f2bf(v.w);
        *(uint2*)&xs[wid][e + half][hl * 4] =
            (uint2){(unsigned)h0 | ((unsigned)h1 << 16), (unsigned)h2 | ((unsigned)h3 << 16)};
    }

    bf16x8 a[4];
    #pragma unroll
    for (int s = 0; s < 4; ++s)
        a[s] = *(const bf16x8*)&xs[wid][c][s * 32 + g * 8];

    f32x4 acc[8];
    #pragma unroll
    for (int t = 0; t < 8; ++t) {
        float bv = b1[t * 16 + c];
        acc[t] = (f32x4){bv, bv, bv, bv};
    }
    #pragma unroll
    for (int t = 0; t < 8; ++t) {
        #pragma unroll
        for (int s = 0; s < 4; ++s) {
            bf16x8 bf = *(const bf16x8*)&W1t[(t * 16 + c) * DIM + s * 32 + g * 8];
            acc[t] = __builtin_amdgcn_mfma_f32_16x16x32_bf16(a[s], bf, acc[t], 0, 0, 0);
        }
    }
    #pragma unroll
    for (int t = 0; t < 8; ++t)
        #pragma unroll
        for (int j = 0; j < 4; ++j)
            xs[wid][g * 4 + j][t * 16 + c] = f2bf(fmaxf(acc[t][j], 0.f));

    #pragma unroll
    for (int s = 0; s < 4; ++s)
        a[s] = *(const bf16x8*)&xs[wid][c][s * 32 + g * 8];

    #pragma unroll
    for (int t = 0; t < 8; ++t) {
        float bv = b2[t * 16 + c];
        acc[t] = (f32x4){bv, bv, bv, bv};
    }
    #pragma unroll
    for (int t = 0; t < 8; ++t) {
        #pragma unroll
        for (int s = 0; s < 4; ++s) {
            bf16x8 bf = *(const bf16x8*)&W2t[(t * 16 + c) * DIM + s * 32 + g * 8];
            acc[t] = __builtin_amdgcn_mfma_f32_16x16x32_bf16(a[s], bf, acc[t], 0, 0, 0);
        }
    }

    #pragma unroll
    for (int t = 0; t < 8; ++t)
        #pragma unroll
        for (int j = 0; j < 4; ++j)
            xs[wid][g * 4 + j][t * 16 + c] = f2bf(fmaxf(acc[t][j], 0.f));

    #pragma unroll
    for (int e = 0; e < 16; ++e) {
        int n = nbase + e;
        if (n < NN)
            *(unsigned*)(Mh + (size_t)n * DIM + lane * 2) = *(const unsigned*)&xs[wid][e][lane * 2];
    }
}

// ---------------------------------------------------------------------------
// L4: FUSED gather + update MLP, software-pipelined.
// Gather: half-wave per node; metadata (deg/off) pre-hoisted into lanes 0-15;
//   next pair's col32 vector prefetched during current gather; 16-deep uint2
//   bursts (8KB in flight/wave). Edge order per lane preserved (bit-identical).
// MLP: h rows preloaded to registers BEFORE the agg-chunk MFMAs so the
//   h-chunk staging never stalls; split-bf16 triple-MFMA; relu; @U2; store.
// Wave-private LDS tile, no barriers.
// ---------------------------------------------------------------------------
__global__ __launch_bounds__(256) void gup_kernel(
    const float* __restrict__ h,
    const unsigned short* __restrict__ Mh, const int* __restrict__ col32,
    const int* __restrict__ off_end, const int* __restrict__ deg,
    const unsigned short* __restrict__ U1h, const unsigned short* __restrict__ U1l,
    const unsigned short* __restrict__ U2h, const unsigned short* __restrict__ U2l,
    const float* __restrict__ c1, const float* __restrict__ c2,
    float* __restrict__ out)
{
    __shared__ unsigned short xs[4][2][16][136];   // hi/lo tiles, wave-private
    const int tid  = threadIdx.x;
    const int lane = tid & 63;
    const int wid  = tid >> 6;
    const int g    = lane >> 4;
    const int c    = lane & 15;
    const int half = lane >> 5;
    const int hl   = lane & 31;
    const int nbase = blockIdx.x * 64 + wid * 16;

    // ---- hoist metadata for the wave's 16 nodes into lanes 0..15 ----
    int dmeta = 0, emeta = 0;
    {
        int nm = nbase + (lane & 15);
        int nc = nm < NN ? nm : NN - 1;
        if (lane < 16) {
            dmeta = (nm < NN) ? deg[nc] : 0;
            emeta = off_end[nc];
        }
    }

    // ---- prefetch pair 0's index vector ----
    int d0  = __shfl(dmeta, half);
    int st0 = __shfl(emeta, half) - d0;
    int idx_pf = (hl < d0) ? col32[st0 + hl] : 0;

    // ---- phase 1: gather agg rows, two nodes per pass (one per half-wave) ----
    #pragma unroll 1
    for (int p = 0; p < 8; ++p) {
        int d     = __shfl(dmeta, 2 * p + half);
        int end   = __shfl(emeta, 2 * p + half);
        int start = end - d;
        int idx   = idx_pf;
        if (p < 7) {   // prefetch next pair's index vector now
            int dn  = __shfl(dmeta, 2 * p + 2 + half);
            int stn = __shfl(emeta, 2 * p + 2 + half) - dn;
            idx_pf  = (hl < dn) ? col32[stn + hl] : 0;
        }
        float s0 = 0.f, s1 = 0.f, s2 = 0.f, s3 = 0.f;
        for (int base = 0; base < d; base += 32) {
            int m = d - base; if (m > 32) m = 32;
            if (base) idx = (hl < m) ? col32[start + base + hl] : 0;
            for (int j = 0; j < m; j += 16) {
                uint2 u[16];
                #pragma unroll
                for (int k = 0; k < 16; ++k) {
                    int si = __shfl(idx, (half << 5) + j + k);   // 0 for invalid lanes
                    u[k] = *(const uint2*)(Mh + (size_t)si * DIM + hl * 4);
                }
                #pragma unroll
                for (int k = 0; k < 16; ++k) {
                    if (j + k < m) {
                        s0 += __uint_as_float(u[k].x << 16);
                        s1 += __uint_as_float(u[k].x & 0xFFFF0000u);
                        s2 += __uint_as_float(u[k].y << 16);
                        s3 += __uint_as_float(u[k].y & 0xFFFF0000u);
                    }
                }
            }
        }
        float inv = 1.0f / fmaxf((float)d, 1.0f);
        s0 *= inv; s1 *= inv; s2 *= inv; s3 *= inv;
        unsigned short h0 = f2bf(s0), h1 = f2bf(s1), h2 = f2bf(s2), h3 = f2bf(s3);
        unsigned short l0 = f2bf(s0 - bf2f(h0)), l1 = f2bf(s1 - bf2f(h1));
        unsigned short l2 = f2bf(s2 - bf2f(h2)), l3 = f2bf(s3 - bf2f(h3));
        *(uint2*)&xs[wid][0][2 * p + half][hl * 4] =
            (uint2){(unsigned)h0 | ((unsigned)h1 << 16), (unsigned)h2 | ((unsigned)h3 << 16)};
        *(uint2*)&xs[wid][1][2 * p + half][hl * 4] =
            (uint2){(unsigned)l0 | ((unsigned)l1 << 16), (unsigned)l2 | ((unsigned)l3 << 16)};
    }

    // ---- issue h row loads early (consumed after the agg-chunk MFMAs) ----
    float4 hreg[8];
    #pragma unroll
    for (int e2 = 0; e2 < 8; ++e2) {
        int n = nbase + e2 * 2 + half;
        int nc = n < NN ? n : NN - 1;
        hreg[e2] = *(const float4*)(h + (size_t)nc * DIM + hl * 4);
    }

    // ---- phase 2a: layer1, agg chunk (U1 rows 128..255) ----
    f32x4 acc[8];
    #pragma unroll
    for (int t = 0; t < 8; ++t) {
        float bv = c1[t * 16 + c];
        acc[t] = (f32x4){bv, bv, bv, bv};
    }
    {
        bf16x8 ah[4], al[4];
        #pragma unroll
        for (int s = 0; s < 4; ++s) {
            ah[s] = *(const bf16x8*)&xs[wid][0][c][s * 32 + g * 8];
            al[s] = *(const bf16x8*)&xs[wid][1][c][s * 32 + g * 8];
        }
        #pragma unroll
        for (int t = 0; t < 8; ++t) {
            #pragma unroll
            for (int s = 0; s < 4; ++s) {
                int kof = 128 + s * 32 + g * 8;
                bf16x8 bh = *(const bf16x8*)&U1h[(t * 16 + c) * 256 + kof];
                bf16x8 bl = *(const bf16x8*)&U1l[(t * 16 + c) * 256 + kof];
                acc[t] = __builtin_amdgcn_mfma_f32_16x16x32_bf16(ah[s], bh, acc[t], 0, 0, 0);
                acc[t] = __builtin_amdgcn_mfma_f32_16x16x32_bf16(al[s], bh, acc[t], 0, 0, 0);
                acc[t] = __builtin_amdgcn_mfma_f32_16x16x32_bf16(ah[s], bl, acc[t], 0, 0, 0);
            }
        }
    }

    // ---- phase 2b: stage preloaded h rows (hi/lo) then h-chunk MFMAs ----
    #pragma unroll
    for (int e2 = 0; e2 < 8; ++e2) {
        float4 v = hreg[e2];
        unsigned short h0 = f2bf(v.x), h1 = f2bf(v.y), h2 = f2bf(v.z), h3 = f2bf(v.w);
        unsigned short l0 = f2bf(v.x - bf2f(h0)), l1 = f2bf(v.y - bf2f(h1));
        unsigned short l2 = f2bf(v.z - bf2f(h2)), l3 = f2bf(v.w - bf2f(h3));
        *(uint2*)&xs[wid][0][e2 * 2 + half][hl * 4] =
            (uint2){(unsigned)h0 | ((unsigned)h1 << 16), (unsigned)h2 | ((unsigned)h3 << 16)};
        *(uint2*)&xs[wid][1][e2 * 2 + half][hl * 4] =
            (uint2){(unsigned)l0 | ((unsigned)l1 << 16), (unsigned)l2 | ((unsigned)l3 << 16)};
    }
    {
        bf16x8 ah[4], al[4];
        #pragma unroll
        for (int s = 0; s < 4; ++s) {
            ah[s] = *(const bf16x8*)&xs[wid][0][c][s * 32 + g * 8];
            al[s] = *(const bf16x8*)&xs[wid][1][c][s * 32 + g * 8];
        }
        #pragma unroll
        for (int t = 0; t < 8; ++t) {
            #pragma unroll
            for (int s = 0; s < 4; ++s) {
                int kof = s * 32 + g * 8;
                bf16x8 bh = *(const bf16x8*)&U1h[(t * 16 + c) * 256 + kof];
                bf16x8 bl = *(const bf16x8*)&U1l[(t * 16 + c) * 256 + kof];
                acc[t] = __builtin_amdgcn_mfma_f32_16x16x32_bf16(ah[s], bh, acc[t], 0, 0, 0);
                acc[t] = __builtin_amdgcn_mfma_f32_16x16x32_bf16(al[s], bh, acc[t], 0, 0, 0);
                acc[t] = __builtin_amdgcn_mfma_f32_16x16x32_bf16(ah[s], bl, acc[t], 0, 0, 0);
            }
        }
    }

    // ---- relu + split -> LDS [row][col] ----
    #pragma unroll
    for (int t = 0; t < 8; ++t)
        #pragma unroll
        for (int j = 0; j < 4; ++j) {
            float yv = fmaxf(acc[t][j], 0.f);
            unsigned short hx = f2bf(yv);
            xs[wid][0][g * 4 + j][t * 16 + c] = hx;
            xs[wid][1][g * 4 + j][t * 16 + c] = f2bf(yv - bf2f(hx));
        }

    // ---- layer 2: K=128 ----
    bf16x8 ah[4], al[4];
    #pragma unroll
    for (int s = 0; s < 4; ++s) {
        ah[s] = *(const bf16x8*)&xs[wid][0][c][s * 32 + g * 8];
        al[s] = *(const bf16x8*)&xs[wid][1][c][s * 32 + g * 8];
    }
    f32x4 acc2[8];
    #pragma unroll
    for (int t = 0; t < 8; ++t) {
        float bv = c2[t * 16 + c];
        acc2[t] = (f32x4){bv, bv, bv, bv};
    }
    #pragma unroll
    for (int t = 0; t < 8; ++t) {
        #pragma unroll
        for (int s = 0; s < 4; ++s) {
            int kof = s * 32 + g * 8;
            bf16x8 bh = *(const bf16x8*)&U2h[(t * 16 + c) * 128 + kof];
            bf16x8 bl = *(const bf16x8*)&U2l[(t * 16 + c) * 128 + kof];
            acc2[t] = __builtin_amdgcn_mfma_f32_16x16x32_bf16(ah[s], bh, acc2[t], 0, 0, 0);
            acc2[t] = __builtin_amdgcn_mfma_f32_16x16x32_bf16(al[s], bh, acc2[t], 0, 0, 0);
            acc2[t] = __builtin_amdgcn_mfma_f32_16x16x32_bf16(ah[s], bl, acc2[t], 0, 0, 0);
        }
    }

    // ---- store: D col=c -> out col t*16+c, row 4g+j ----
    #pragma unroll
    for (int t = 0; t < 8; ++t)
        #pragma unroll
        for (int j = 0; j < 4; ++j) {
            int n = nbase + g * 4 + j;
            if (n < NN) out[(size_t)n * DIM + t * 16 + c] = acc2[t][j];
        }
}

// ---------------------------------------------------------------------------
// Fallback kernels (small workspace): detect + prep_w + atomic msg + fp32 upd.
// ---------------------------------------------------------------------------
__global__ void detect_i64_kernel(const int* __restrict__ ei, int* __restrict__ flag) {
    int l = threadIdx.x;           // 64 threads
    int v = ei[2 * l + 1];
    unsigned long long b = __ballot(v != 0);
    if (l == 0) flag[0] = (b == 0ULL) ? 1 : 0;
}

__global__ __launch_bounds__(256) void prep_w_kernel(
    const float* __restrict__ W1, const float* __restrict__ W2,
    unsigned short* __restrict__ W1t, unsigned short* __restrict__ W2t)
{
    int idx = blockIdx.x * 256 + threadIdx.x;     // 32768 total
    int m   = idx >> 14;
    int rem = idx & 16383;
    int n = rem >> 7, k = rem & 127;
    const float* W = m ? W2 : W1;
    unsigned short* Wt = m ? W2t : W1t;
    Wt[n * DIM + k] = f2bf(W[k * DIM + n]);
}

__global__ __launch_bounds__(256) void deg_i_kernel(const void* __restrict__ ei,
                                                    const int* __restrict__ flag,
                                                    int* __restrict__ deg) {
    bool i64 = flag[0] != 0;
    int e = blockIdx.x * 256 + threadIdx.x;
    if (e < EE) {
        int r = load_idx(ei, i64, e);
        atomicAdd(&deg[r], 1);
    }
}

__global__ __launch_bounds__(256) void msg_kernel(
    const float* __restrict__ h, const void* __restrict__ ei, const int* __restrict__ flag,
    const unsigned short* __restrict__ W1t, const float* __restrict__ b1,
    const unsigned short* __restrict__ W2t, const float* __restrict__ b2,
    float* __restrict__ agg)
{
    __shared__ unsigned short xs[4][16][136];
    const int tid  = threadIdx.x;
    const int lane = tid & 63;
    const int wid  = tid >> 6;
    const int g    = lane >> 4;
    const int c    = lane & 15;
    const bool i64 = flag[0] != 0;
    const int ebase = blockIdx.x * 64 + wid * 16;

    #pragma unroll
    for (int e = 0; e < 16; ++e) {
        int src = load_idx(ei, i64, (long long)EE + (ebase + e));
        float2 v = *(const float2*)(h + (size_t)src * DIM + lane * 2);
        unsigned p = (unsigned)f2bf(v.x) | ((unsigned)f2bf(v.y) << 16);
        *(unsigned*)&xs[wid][e][lane * 2] = p;
    }
    __syncthreads();

    bf16x8 a[4];
    #pragma unroll
    for (int s = 0; s < 4; ++s)
        a[s] = *(const bf16x8*)&xs[wid][c][s * 32 + g * 8];

    f32x4 acc[8];
    #pragma unroll
    for (int t = 0; t < 8; ++t) {
        float bv = b1[t * 16 + c];
        acc[t] = (f32x4){bv, bv, bv, bv};
    }
    #pragma unroll
    for (int t = 0; t < 8; ++t) {
        #pragma unroll
        for (int s = 0; s < 4; ++s) {
            bf16x8 bf = *(const bf16x8*)&W1t[(t * 16 + c) * DIM + s * 32 + g * 8];
            acc[t] = __builtin_amdgcn_mfma_f32_16x16x32_bf16(a[s], bf, acc[t], 0, 0, 0);
        }
    }
    __syncthreads();
    #pragma unroll
    for (int t = 0; t < 8; ++t)
        #pragma unroll
        for (int j = 0; j < 4; ++j)
            xs[wid][g * 4 + j][t * 16 + c] = f2bf(fmaxf(acc[t][j], 0.f));
    __syncthreads();

    #pragma unroll
    for (int s = 0; s < 4; ++s)
        a[s] = *(const bf16x8*)&xs[wid][c][s * 32 + g * 8];

    #pragma unroll
    for (int t = 0; t < 8; ++t) {
        float bv = b2[t * 16 + c];
        acc[t] = (f32x4){bv, bv, bv, bv};
    }
    #pragma unroll
    for (int t = 0; t < 8; ++t) {
        #pragma unroll
        for (int s = 0; s < 4; ++s) {
            bf16x8 bf = *(const bf16x8*)&W2t[(t * 16 + c) * DIM + s * 32 + g * 8];
            acc[t] = __builtin_amdgcn_mfma_f32_16x16x32_bf16(a[s], bf, acc[t], 0, 0, 0);
        }
    }

    #pragma unroll
    for (int j = 0; j < 4; ++j) {
        int r = load_idx(ei, i64, ebase + g * 4 + j);
        #pragma unroll
        for (int t = 0; t < 8; ++t)
            atomicAdd(&agg[(size_t)r * DIM + t * 16 + c], fmaxf(acc[t][j], 0.f));
    }
}

__global__ __launch_bounds__(256) void upd_kernel(
    const float* __restrict__ h, const float* __restrict__ aggout,
    const int* __restrict__ deg,
    const float* __restrict__ U1, const float* __restrict__ c1,
    const float* __restrict__ U2, const float* __restrict__ c2,
    float* __restrict__ out)
{
    __shared__ float zs[4][8][2 * DIM];   // 32 KiB
    const int tid  = threadIdx.x;
    const int lane = tid & 63;
    const int wid  = tid >> 6;
    const int nbase = blockIdx.x * 32 + wid * 8;

    #pragma unroll
    for (int i = 0; i < 8; ++i) {
        int n = nbase + i;
        if (n < NN) {
            float2 hv = *(const float2*)(h + (size_t)n * DIM + lane * 2);
            *(float2*)&zs[wid][i][lane * 2] = hv;
            float d = fmaxf((float)deg[n], 1.0f);
            float inv = 1.0f / d;
            float2 av = *(const float2*)(aggout + (size_t)n * DIM + lane * 2);
            av.x *= inv; av.y *= inv;
            *(float2*)&zs[wid][i][DIM + lane * 2] = av;
        }
    }
    __syncthreads();

    float acc0[8], acc1[8];
    {
        float cc0 = c1[lane], cc1 = c1[lane + 64];
        #pragma unroll
        for (int i = 0; i < 8; ++i) { acc0[i] = cc0; acc1[i] = cc1; }
    }
    for (int k = 0; k < 2 * DIM; k += 4) {
        float wa[4], wb[4];
        #pragma unroll
        for (int kk = 0; kk < 4; ++kk) {
            wa[kk] = U1[(k + kk) * DIM + lane];
            wb[kk] = U1[(k + kk) * DIM + lane + 64];
        }
        #pragma unroll
        for (int i = 0; i < 8; ++i) {
            float4 zv = *(const float4*)&zs[wid][i][k];
            acc0[i] = fmaf(zv.x, wa[0], acc0[i]);
            acc1[i] = fmaf(zv.x, wb[0], acc1[i]);
            acc0[i] = fmaf(zv.y, wa[1], acc0[i]);
            acc1[i] = fmaf(zv.y, wb[1], acc1[i]);
            acc0[i] = fmaf(zv.z, wa[2], acc0[i]);
            acc1[i] = fmaf(zv.z, wb[2], acc1[i]);
            acc0[i] = fmaf(zv.w, wa[3], acc0[i]);
            acc1[i] = fmaf(zv.w, wb[3], acc1[i]);
        }
    }
    __syncthreads();
    #pragma unroll
    for (int i = 0; i < 8; ++i) {
        zs[wid][i][lane]      = fmaxf(acc0[i], 0.f);
        zs[wid][i][lane + 64] = fmaxf(acc1[i], 0.f);
    }
    __syncthreads();

    {
        float cc0 = c2[lane], cc1 = c2[lane + 64];
        #pragma unroll
        for (int i = 0; i < 8; ++i) { acc0[i] = cc0; acc1[i] = cc1; }
    }
    for (int k = 0; k < DIM; k += 4) {
        float wa[4], wb[4];
        #pragma unroll
        for (int kk = 0; kk < 4; ++kk) {
            wa[kk] = U2[(k + kk) * DIM + lane];
            wb[kk] = U2[(k + kk) * DIM + lane + 64];
        }
        #pragma unroll
        for (int i = 0; i < 8; ++i) {
            float4 zv = *(const float4*)&zs[wid][i][k];
            acc0[i] = fmaf(zv.x, wa[0], acc0[i]);
            acc1[i] = fmaf(zv.x, wb[0], acc1[i]);
            acc0[i] = fmaf(zv.y, wa[1], acc0[i]);
            acc1[i] = fmaf(zv.y, wb[1], acc1[i]);
            acc0[i] = fmaf(zv.z, wa[2], acc0[i]);
            acc1[i] = fmaf(zv.z, wb[2], acc1[i]);
            acc0[i] = fmaf(zv.w, wa[3], acc0[i]);
            acc1[i] = fmaf(zv.w, wb[3], acc1[i]);
        }
    }

    #pragma unroll
    for (int i = 0; i < 8; ++i) {
        int n = nbase + i;
        if (n < NN) {
            out[(size_t)n * DIM + lane]      = acc0[i];
            out[(size_t)n * DIM + lane + 64] = acc1[i];
        }
    }
}

extern "C" void kernel_launch(void* const* d_in, const int* in_sizes, int n_in,
                              void* d_out, int out_size, void* d_ws, size_t ws_size,
                              hipStream_t stream) {
    const float* h  = (const float*)d_in[0];
    const void*  ei = d_in[1];
    const float* W1 = (const float*)d_in[2];
    const float* b1 = (const float*)d_in[3];
    const float* W2 = (const float*)d_in[4];
    const float* b2 = (const float*)d_in[5];
    const float* U1 = (const float*)d_in[6];
    const float* c1 = (const float*)d_in[7];
    const float* U2 = (const float*)d_in[8];
    const float* c2 = (const float*)d_in[9];
    float* out = (float*)d_out;

    // ws layout (big path):
    //   Mh    @ 0           bf16 [NN][128]   12,800,000 B
    //   col32 @ 12,800,000  int  [EE]         3,200,000 B
    //   deg   @ 16,000,000  int  [NN]           200,000 B
    //   off   @ 16,200,000  int  [NN]           200,000 B
    //   flag  @ 16,400,000  int                      64 B
    //   W1t   @ 16,400,064  bf16 [128][128]      32,768 B
    //   W2t   @ 16,432,832  bf16 [128][128]      32,768 B
    //   U1h   @ 16,465,600  bf16 [128][256]      65,536 B
    //   U1l   @ 16,531,136  bf16 [128][256]      65,536 B
    //   U2h   @ 16,596,672  bf16 [128][128]      32,768 B
    //   U2l   @ 16,629,440  bf16 [128][128]      32,768 B
    const size_t BIG_BYTES = 16662208;
    const bool big = ws_size >= BIG_BYTES;

    char* wsb = (char*)d_ws;
    unsigned short *Mh, *W1t, *W2t, *U1h, *U1l, *U2h, *U2l;
    int *col32, *deg, *off, *flag;
    if (big) {
        Mh    = (unsigned short*)wsb;
        col32 = (int*)(wsb + 12800000);
        deg   = (int*)(wsb + 16000000);
        off   = (int*)(wsb + 16200000);
        flag  = (int*)(wsb + 16400000);
        W1t   = (unsigned short*)(wsb + 16400064);
        W2t   = (unsigned short*)(wsb + 16432832);
        U1h   = (unsigned short*)(wsb + 16465600);
        U1l   = (unsigned short*)(wsb + 16531136);
        U2h   = (unsigned short*)(wsb + 16596672);
        U2l   = (unsigned short*)(wsb + 16629440);
    } else {
        Mh    = nullptr; col32 = nullptr;
        U1h = U1l = U2h = U2l = nullptr;
        deg   = (int*)wsb;
        off   = (int*)(wsb + 200000);
        flag  = (int*)(wsb + 400000);
        W1t   = (unsigned short*)(wsb + 400064);
        W2t   = (unsigned short*)(wsb + 400064 + 32768);
    }

    if (big) {
        prep_zero_kernel<<<PREP_BLKS + ZERO_BLKS, 256, 0, stream>>>(
            W1, W2, U1, U2, W1t, W2t, U1h, U1l, U2h, U2l, deg);
        deg_fast_kernel<<<FILL_BLKS, 256, 0, stream>>>(ei, deg);
        scan_kernel<<<1, 1024, 0, stream>>>(deg, off);
        fill_mlp_kernel<<<FILL_BLKS + MLP_BLKS, 256, 0, stream>>>(
            ei, h, W1t, b1, W2t, b2, off, col32, Mh);
        gup_kernel<<<MLP_BLKS, 256, 0, stream>>>(h, Mh, col32, off, deg,
                                                 U1h, U1l, U2h, U2l, c1, c2, out);
    } else {
        detect_i64_kernel<<<1, 64, 0, stream>>>((const int*)ei, flag);
        prep_w_kernel<<<128, 256, 0, stream>>>(W1, W2, W1t, W2t);
        hipMemsetAsync(deg, 0, (size_t)NN * sizeof(int), stream);
        deg_i_kernel<<<(EE + 255) / 256, 256, 0, stream>>>(ei, flag, deg);
        hipMemsetAsync(d_out, 0, (size_t)NN * DIM * sizeof(float), stream);
        msg_kernel<<<EE / 64, 256, 0, stream>>>(h, ei, flag, W1t, b1, W2t, b2, out);
        upd_kernel<<<(NN + 31) / 32, 256, 0, stream>>>(h, out, deg, U1, c1, U2, c2, out);
    }
}

// Round 6
// 287.082 us; speedup vs baseline: 2.5519x; 1.0044x over previous
//
#include <hip/hip_runtime.h>
#include <cstddef>

#define NN 50000
#define EE 800000
#define DIM 128

#define PREP_BLKS 320
#define ZERO_BLKS 49
#define FILL_BLKS 3125
#define MLP_BLKS  782   // ceil(NN/64)

typedef __attribute__((ext_vector_type(8))) short bf16x8;
typedef __attribute__((ext_vector_type(4))) float f32x4;

// ---------------------------------------------------------------------------
// helpers
// ---------------------------------------------------------------------------
__device__ __forceinline__ unsigned short f2bf(float x) {
    unsigned u = __float_as_uint(x);
    unsigned r = (u + 0x7FFFu + ((u >> 16) & 1u)) >> 16;   // RNE
    return (unsigned short)r;
}

__device__ __forceinline__ float bf2f(unsigned short b) {
    return __uint_as_float((unsigned)b << 16);
}

__device__ __forceinline__ int load_idx(const void* ei, bool i64, long long i) {
    return i64 ? (int)((const long long*)ei)[i] : ((const int*)ei)[i];
}

// per-wave i64 detection: identical ballot to the old detect kernel
__device__ __forceinline__ bool detect_i64_inline(const void* ei) {
    int l = threadIdx.x & 63;
    int v = ((const int*)ei)[2 * l + 1];
    return __ballot(v != 0) == 0ULL;
}

// ---------------------------------------------------------------------------
// L0: weight prep (W bf16-T; U split hi/lo bf16-T) + deg zeroing, one launch
// ---------------------------------------------------------------------------
__global__ __launch_bounds__(256) void prep_zero_kernel(
    const float* __restrict__ W1, const float* __restrict__ W2,
    const float* __restrict__ U1, const float* __restrict__ U2,
    unsigned short* __restrict__ W1t, unsigned short* __restrict__ W2t,
    unsigned short* __restrict__ U1h, unsigned short* __restrict__ U1l,
    unsigned short* __restrict__ U2h, unsigned short* __restrict__ U2l,
    int* __restrict__ deg)
{
    int bid = blockIdx.x;
    if (bid < PREP_BLKS) {
        int idx = bid * 256 + threadIdx.x;     // 81920 total
        if (idx < 32768) {
            int m   = idx >> 14;
            int rem = idx & 16383;
            int n = rem >> 7, k = rem & 127;
            const float* W = m ? W2 : W1;
            unsigned short* Wt = m ? W2t : W1t;
            Wt[n * DIM + k] = f2bf(W[k * DIM + n]);
        } else if (idx < 65536) {
            int r = idx - 32768;                      // U1: [256][128]
            int k = r >> 7, n = r & 127;
            float w = U1[r];
            unsigned short hx = f2bf(w);
            U1h[n * 256 + k] = hx;
            U1l[n * 256 + k] = f2bf(w - bf2f(hx));
        } else {
            int r = idx - 65536;                      // U2: [128][128]
            int k = r >> 7, n = r & 127;
            float w = U2[r];
            unsigned short hx = f2bf(w);
            U2h[n * 128 + k] = hx;
            U2l[n * 128 + k] = f2bf(w - bf2f(hx));
        }
    } else {
        int base = (bid - PREP_BLKS) * 1024 + threadIdx.x * 4;
        if (base + 4 <= NN) {
            *(int4*)(deg + base) = (int4){0, 0, 0, 0};
        } else {
            #pragma unroll
            for (int k = 0; k < 4; ++k)
                if (base + k < NN) deg[base + k] = 0;
        }
    }
}

// ---------------------------------------------------------------------------
// L1: degree count (inline i64 detect)
// ---------------------------------------------------------------------------
__global__ __launch_bounds__(256) void deg_fast_kernel(const void* __restrict__ ei,
                                                       int* __restrict__ deg) {
    bool i64 = detect_i64_inline(ei);
    int e = blockIdx.x * 256 + threadIdx.x;
    if (e < EE) {
        int r = load_idx(ei, i64, e);
        atomicAdd(&deg[r], 1);
    }
}

// ---------------------------------------------------------------------------
// L2: exclusive prefix scan, single block of 1024 threads, int4-vectorized
// ---------------------------------------------------------------------------
__global__ __launch_bounds__(1024) void scan_kernel(const int* __restrict__ deg,
                                                    int* __restrict__ off) {
    const int C = 52;                 // 1024*52 = 53248 >= NN
    int t = threadIdx.x;
    int base = t * C;
    int sum = 0;
    if (base + C <= NN) {
        const int4* p = (const int4*)(deg + base);
        #pragma unroll 13
        for (int i = 0; i < C / 4; ++i) { int4 v = p[i]; sum += v.x + v.y + v.z + v.w; }
    } else {
        for (int i = 0; i < C; ++i) { int n = base + i; if (n < NN) sum += deg[n]; }
    }
    __shared__ int ps[1024];
    ps[t] = sum;
    __syncthreads();
    for (int s = 1; s < 1024; s <<= 1) {
        int v = (t >= s) ? ps[t - s] : 0;
        __syncthreads();
        ps[t] += v;
        __syncthreads();
    }
    int run = (t == 0) ? 0 : ps[t - 1];
    if (base + C <= NN) {
        const int4* dp = (const int4*)(deg + base);
        int4* op = (int4*)(off + base);
        for (int i = 0; i < C / 4; ++i) {
            int4 v = dp[i];
            int4 o;
            o.x = run; run += v.x;
            o.y = run; run += v.y;
            o.z = run; run += v.z;
            o.w = run; run += v.w;
            op[i] = o;
        }
    } else {
        for (int i = 0; i < C; ++i) {
            int n = base + i;
            if (n < NN) { off[n] = run; run += deg[n]; }
        }
    }
}

// ---------------------------------------------------------------------------
// L3: fill (CSR slot claim) + node-level message MLP, one launch.
// ---------------------------------------------------------------------------
__global__ __launch_bounds__(256) void fill_mlp_kernel(
    const void* __restrict__ ei, const float* __restrict__ h,
    const unsigned short* __restrict__ W1t, const float* __restrict__ b1,
    const unsigned short* __restrict__ W2t, const float* __restrict__ b2,
    int* __restrict__ off, int* __restrict__ col32,
    unsigned short* __restrict__ Mh)
{
    __shared__ unsigned short xs[4][16][136];   // bf16, +8 pad (mlp part only)

    if (blockIdx.x < FILL_BLKS) {
        bool i64 = detect_i64_inline(ei);
        int e = blockIdx.x * 256 + threadIdx.x;
        if (e < EE) {
            int r = load_idx(ei, i64, e);
            int c = load_idx(ei, i64, (long long)EE + e);
            int slot = atomicAdd(&off[r], 1);
            col32[slot] = c;
        }
        return;
    }

    const int tid  = threadIdx.x;
    const int lane = tid & 63;
    const int wid  = tid >> 6;
    const int g    = lane >> 4;     // k-group
    const int c    = lane & 15;     // col / row-in-tile
    const int half = lane >> 5;
    const int hl   = lane & 31;
    const int nbase = (blockIdx.x - FILL_BLKS) * 64 + wid * 16;

    // float4 row staging: lanes 0-31 row e, lanes 32-63 row e+1 (16B/lane)
    #pragma unroll
    for (int e = 0; e < 16; e += 2) {
        int n = nbase + e + half;
        int nc = n < NN ? n : NN - 1;
        float4 v = *(const float4*)(h + (size_t)nc * DIM + hl * 4);
        unsigned short h0 = f2bf(v.x), h1 = f2bf(v.y), h2 = f2bf(v.z), h3 = f2bf(v.w);
        *(uint2*)&xs[wid][e + half][hl * 4] =
            (uint2){(unsigned)h0 | ((unsigned)h1 << 16), (unsigned)h2 | ((unsigned)h3 << 16)};
    }

    bf16x8 a[4];
    #pragma unroll
    for (int s = 0; s < 4; ++s)
        a[s] = *(const bf16x8*)&xs[wid][c][s * 32 + g * 8];

    f32x4 acc[8];
    #pragma unroll
    for (int t = 0; t < 8; ++t) {
        float bv = b1[t * 16 + c];
        acc[t] = (f32x4){bv, bv, bv, bv};
    }
    #pragma unroll
    for (int t = 0; t < 8; ++t) {
        #pragma unroll
        for (int s = 0; s < 4; ++s) {
            bf16x8 bf = *(const bf16x8*)&W1t[(t * 16 + c) * DIM + s * 32 + g * 8];
            acc[t] = __builtin_amdgcn_mfma_f32_16x16x32_bf16(a[s], bf, acc[t], 0, 0, 0);
        }
    }
    #pragma unroll
    for (int t = 0; t < 8; ++t)
        #pragma unroll
        for (int j = 0; j < 4; ++j)
            xs[wid][g * 4 + j][t * 16 + c] = f2bf(fmaxf(acc[t][j], 0.f));

    #pragma unroll
    for (int s = 0; s < 4; ++s)
        a[s] = *(const bf16x8*)&xs[wid][c][s * 32 + g * 8];

    #pragma unroll
    for (int t = 0; t < 8; ++t) {
        float bv = b2[t * 16 + c];
        acc[t] = (f32x4){bv, bv, bv, bv};
    }
    #pragma unroll
    for (int t = 0; t < 8; ++t) {
        #pragma unroll
        for (int s = 0; s < 4; ++s) {
            bf16x8 bf = *(const bf16x8*)&W2t[(t * 16 + c) * DIM + s * 32 + g * 8];
            acc[t] = __builtin_amdgcn_mfma_f32_16x16x32_bf16(a[s], bf, acc[t], 0, 0, 0);
        }
    }

    #pragma unroll
    for (int t = 0; t < 8; ++t)
        #pragma unroll
        for (int j = 0; j < 4; ++j)
            xs[wid][g * 4 + j][t * 16 + c] = f2bf(fmaxf(acc[t][j], 0.f));

    #pragma unroll
    for (int e = 0; e < 16; ++e) {
        int n = nbase + e;
        if (n < NN)
            *(unsigned*)(Mh + (size_t)n * DIM + lane * 2) = *(const unsigned*)&xs[wid][e][lane * 2];
    }
}

// ---------------------------------------------------------------------------
// L4: FUSED gather + update MLP.
// __launch_bounds__(256, 4): LDS (34.8KB/block) already caps residency at
// 4 blocks/CU = 4 waves/SIMD, so declaring 4 waves/EU doubles the VGPR
// budget (64 -> 128) at ZERO occupancy cost. This is what lets the 16-deep
// gather burst (u[16] = 32 VGPRs) actually stay in flight instead of being
// serialized into dependent ~700-cy load round-trips (R5: VGPR_Count=64).
// ---------------------------------------------------------------------------
__global__ __launch_bounds__(256, 4) void gup_kernel(
    const float* __restrict__ h,
    const unsigned short* __restrict__ Mh, const int* __restrict__ col32,
    const int* __restrict__ off_end, const int* __restrict__ deg,
    const unsigned short* __restrict__ U1h, const unsigned short* __restrict__ U1l,
    const unsigned short* __restrict__ U2h, const unsigned short* __restrict__ U2l,
    const float* __restrict__ c1, const float* __restrict__ c2,
    float* __restrict__ out)
{
    __shared__ unsigned short xs[4][2][16][136];   // hi/lo tiles, wave-private
    const int tid  = threadIdx.x;
    const int lane = tid & 63;
    const int wid  = tid >> 6;
    const int g    = lane >> 4;
    const int c    = lane & 15;
    const int half = lane >> 5;
    const int hl   = lane & 31;
    const int nbase = blockIdx.x * 64 + wid * 16;

    // ---- hoist metadata for the wave's 16 nodes into lanes 0..15 ----
    int dmeta = 0, emeta = 0;
    {
        int nm = nbase + (lane & 15);
        int nc = nm < NN ? nm : NN - 1;
        if (lane < 16) {
            dmeta = (nm < NN) ? deg[nc] : 0;
            emeta = off_end[nc];
        }
    }

    // ---- prefetch pair 0's index vector ----
    int d0  = __shfl(dmeta, half);
    int st0 = __shfl(emeta, half) - d0;
    int idx_pf = (hl < d0) ? col32[st0 + hl] : 0;

    // ---- phase 1: gather agg rows, two nodes per pass (one per half-wave) ----
    #pragma unroll 1
    for (int p = 0; p < 8; ++p) {
        int d     = __shfl(dmeta, 2 * p + half);
        int end   = __shfl(emeta, 2 * p + half);
        int start = end - d;
        int idx   = idx_pf;
        if (p < 7) {   // prefetch next pair's index vector now
            int dn  = __shfl(dmeta, 2 * p + 2 + half);
            int stn = __shfl(emeta, 2 * p + 2 + half) - dn;
            idx_pf  = (hl < dn) ? col32[stn + hl] : 0;
        }
        float s0 = 0.f, s1 = 0.f, s2 = 0.f, s3 = 0.f;
        for (int base = 0; base < d; base += 32) {
            int m = d - base; if (m > 32) m = 32;
            if (base) idx = (hl < m) ? col32[start + base + hl] : 0;
            for (int j = 0; j < m; j += 16) {
                uint2 u[16];
                #pragma unroll
                for (int k = 0; k < 16; ++k) {
                    int si = __shfl(idx, (half << 5) + j + k);   // 0 for invalid lanes
                    u[k] = *(const uint2*)(Mh + (size_t)si * DIM + hl * 4);
                }
                #pragma unroll
                for (int k = 0; k < 16; ++k) {
                    if (j + k < m) {
                        s0 += __uint_as_float(u[k].x << 16);
                        s1 += __uint_as_float(u[k].x & 0xFFFF0000u);
                        s2 += __uint_as_float(u[k].y << 16);
                        s3 += __uint_as_float(u[k].y & 0xFFFF0000u);
                    }
                }
            }
        }
        float inv = 1.0f / fmaxf((float)d, 1.0f);
        s0 *= inv; s1 *= inv; s2 *= inv; s3 *= inv;
        unsigned short h0 = f2bf(s0), h1 = f2bf(s1), h2 = f2bf(s2), h3 = f2bf(s3);
        unsigned short l0 = f2bf(s0 - bf2f(h0)), l1 = f2bf(s1 - bf2f(h1));
        unsigned short l2 = f2bf(s2 - bf2f(h2)), l3 = f2bf(s3 - bf2f(h3));
        *(uint2*)&xs[wid][0][2 * p + half][hl * 4] =
            (uint2){(unsigned)h0 | ((unsigned)h1 << 16), (unsigned)h2 | ((unsigned)h3 << 16)};
        *(uint2*)&xs[wid][1][2 * p + half][hl * 4] =
            (uint2){(unsigned)l0 | ((unsigned)l1 << 16), (unsigned)l2 | ((unsigned)l3 << 16)};
    }

    // ---- issue h row loads early (consumed after the agg-chunk MFMAs) ----
    float4 hreg[8];
    #pragma unroll
    for (int e2 = 0; e2 < 8; ++e2) {
        int n = nbase + e2 * 2 + half;
        int nc = n < NN ? n : NN - 1;
        hreg[e2] = *(const float4*)(h + (size_t)nc * DIM + hl * 4);
    }

    // ---- phase 2a: layer1, agg chunk (U1 rows 128..255) ----
    f32x4 acc[8];
    #pragma unroll
    for (int t = 0; t < 8; ++t) {
        float bv = c1[t * 16 + c];
        acc[t] = (f32x4){bv, bv, bv, bv};
    }
    {
        bf16x8 ah[4], al[4];
        #pragma unroll
        for (int s = 0; s < 4; ++s) {
            ah[s] = *(const bf16x8*)&xs[wid][0][c][s * 32 + g * 8];
            al[s] = *(const bf16x8*)&xs[wid][1][c][s * 32 + g * 8];
        }
        #pragma unroll
        for (int t = 0; t < 8; ++t) {
            #pragma unroll
            for (int s = 0; s < 4; ++s) {
                int kof = 128 + s * 32 + g * 8;
                bf16x8 bh = *(const bf16x8*)&U1h[(t * 16 + c) * 256 + kof];
                bf16x8 bl = *(const bf16x8*)&U1l[(t * 16 + c) * 256 + kof];
                acc[t] = __builtin_amdgcn_mfma_f32_16x16x32_bf16(ah[s], bh, acc[t], 0, 0, 0);
                acc[t] = __builtin_amdgcn_mfma_f32_16x16x32_bf16(al[s], bh, acc[t], 0, 0, 0);
                acc[t] = __builtin_amdgcn_mfma_f32_16x16x32_bf16(ah[s], bl, acc[t], 0, 0, 0);
            }
        }
    }

    // ---- phase 2b: stage preloaded h rows (hi/lo) then h-chunk MFMAs ----
    #pragma unroll
    for (int e2 = 0; e2 < 8; ++e2) {
        float4 v = hreg[e2];
        unsigned short h0 = f2bf(v.x), h1 = f2bf(v.y), h2 = f2bf(v.z), h3 = f2bf(v.w);
        unsigned short l0 = f2bf(v.x - bf2f(h0)), l1 = f2bf(v.y - bf2f(h1));
        unsigned short l2 = f2bf(v.z - bf2f(h2)), l3 = f2bf(v.w - bf2f(h3));
        *(uint2*)&xs[wid][0][e2 * 2 + half][hl * 4] =
            (uint2){(unsigned)h0 | ((unsigned)h1 << 16), (unsigned)h2 | ((unsigned)h3 << 16)};
        *(uint2*)&xs[wid][1][e2 * 2 + half][hl * 4] =
            (uint2){(unsigned)l0 | ((unsigned)l1 << 16), (unsigned)l2 | ((unsigned)l3 << 16)};
    }
    {
        bf16x8 ah[4], al[4];
        #pragma unroll
        for (int s = 0; s < 4; ++s) {
            ah[s] = *(const bf16x8*)&xs[wid][0][c][s * 32 + g * 8];
            al[s] = *(const bf16x8*)&xs[wid][1][c][s * 32 + g * 8];
        }
        #pragma unroll
        for (int t = 0; t < 8; ++t) {
            #pragma unroll
            for (int s = 0; s < 4; ++s) {
                int kof = s * 32 + g * 8;
                bf16x8 bh = *(const bf16x8*)&U1h[(t * 16 + c) * 256 + kof];
                bf16x8 bl = *(const bf16x8*)&U1l[(t * 16 + c) * 256 + kof];
                acc[t] = __builtin_amdgcn_mfma_f32_16x16x32_bf16(ah[s], bh, acc[t], 0, 0, 0);
                acc[t] = __builtin_amdgcn_mfma_f32_16x16x32_bf16(al[s], bh, acc[t], 0, 0, 0);
                acc[t] = __builtin_amdgcn_mfma_f32_16x16x32_bf16(ah[s], bl, acc[t], 0, 0, 0);
            }
        }
    }

    // ---- relu + split -> LDS [row][col] ----
    #pragma unroll
    for (int t = 0; t < 8; ++t)
        #pragma unroll
        for (int j = 0; j < 4; ++j) {
            float yv = fmaxf(acc[t][j], 0.f);
            unsigned short hx = f2bf(yv);
            xs[wid][0][g * 4 + j][t * 16 + c] = hx;
            xs[wid][1][g * 4 + j][t * 16 + c] = f2bf(yv - bf2f(hx));
        }

    // ---- layer 2: K=128 ----
    bf16x8 ah[4], al[4];
    #pragma unroll
    for (int s = 0; s < 4; ++s) {
        ah[s] = *(const bf16x8*)&xs[wid][0][c][s * 32 + g * 8];
        al[s] = *(const bf16x8*)&xs[wid][1][c][s * 32 + g * 8];
    }
    f32x4 acc2[8];
    #pragma unroll
    for (int t = 0; t < 8; ++t) {
        float bv = c2[t * 16 + c];
        acc2[t] = (f32x4){bv, bv, bv, bv};
    }
    #pragma unroll
    for (int t = 0; t < 8; ++t) {
        #pragma unroll
        for (int s = 0; s < 4; ++s) {
            int kof = s * 32 + g * 8;
            bf16x8 bh = *(const bf16x8*)&U2h[(t * 16 + c) * 128 + kof];
            bf16x8 bl = *(const bf16x8*)&U2l[(t * 16 + c) * 128 + kof];
            acc2[t] = __builtin_amdgcn_mfma_f32_16x16x32_bf16(ah[s], bh, acc2[t], 0, 0, 0);
            acc2[t] = __builtin_amdgcn_mfma_f32_16x16x32_bf16(al[s], bh, acc2[t], 0, 0, 0);
            acc2[t] = __builtin_amdgcn_mfma_f32_16x16x32_bf16(ah[s], bl, acc2[t], 0, 0, 0);
        }
    }

    // ---- store: D col=c -> out col t*16+c, row 4g+j ----
    #pragma unroll
    for (int t = 0; t < 8; ++t)
        #pragma unroll
        for (int j = 0; j < 4; ++j) {
            int n = nbase + g * 4 + j;
            if (n < NN) out[(size_t)n * DIM + t * 16 + c] = acc2[t][j];
        }
}

// ---------------------------------------------------------------------------
// Fallback kernels (small workspace): detect + prep_w + atomic msg + fp32 upd.
// ---------------------------------------------------------------------------
__global__ void detect_i64_kernel(const int* __restrict__ ei, int* __restrict__ flag) {
    int l = threadIdx.x;           // 64 threads
    int v = ei[2 * l + 1];
    unsigned long long b = __ballot(v != 0);
    if (l == 0) flag[0] = (b == 0ULL) ? 1 : 0;
}

__global__ __launch_bounds__(256) void prep_w_kernel(
    const float* __restrict__ W1, const float* __restrict__ W2,
    unsigned short* __restrict__ W1t, unsigned short* __restrict__ W2t)
{
    int idx = blockIdx.x * 256 + threadIdx.x;     // 32768 total
    int m   = idx >> 14;
    int rem = idx & 16383;
    int n = rem >> 7, k = rem & 127;
    const float* W = m ? W2 : W1;
    unsigned short* Wt = m ? W2t : W1t;
    Wt[n * DIM + k] = f2bf(W[k * DIM + n]);
}

__global__ __launch_bounds__(256) void deg_i_kernel(const void* __restrict__ ei,
                                                    const int* __restrict__ flag,
                                                    int* __restrict__ deg) {
    bool i64 = flag[0] != 0;
    int e = blockIdx.x * 256 + threadIdx.x;
    if (e < EE) {
        int r = load_idx(ei, i64, e);
        atomicAdd(&deg[r], 1);
    }
}

__global__ __launch_bounds__(256) void msg_kernel(
    const float* __restrict__ h, const void* __restrict__ ei, const int* __restrict__ flag,
    const unsigned short* __restrict__ W1t, const float* __restrict__ b1,
    const unsigned short* __restrict__ W2t, const float* __restrict__ b2,
    float* __restrict__ agg)
{
    __shared__ unsigned short xs[4][16][136];
    const int tid  = threadIdx.x;
    const int lane = tid & 63;
    const int wid  = tid >> 6;
    const int g    = lane >> 4;
    const int c    = lane & 15;
    const bool i64 = flag[0] != 0;
    const int ebase = blockIdx.x * 64 + wid * 16;

    #pragma unroll
    for (int e = 0; e < 16; ++e) {
        int src = load_idx(ei, i64, (long long)EE + (ebase + e));
        float2 v = *(const float2*)(h + (size_t)src * DIM + lane * 2);
        unsigned p = (unsigned)f2bf(v.x) | ((unsigned)f2bf(v.y) << 16);
        *(unsigned*)&xs[wid][e][lane * 2] = p;
    }
    __syncthreads();

    bf16x8 a[4];
    #pragma unroll
    for (int s = 0; s < 4; ++s)
        a[s] = *(const bf16x8*)&xs[wid][c][s * 32 + g * 8];

    f32x4 acc[8];
    #pragma unroll
    for (int t = 0; t < 8; ++t) {
        float bv = b1[t * 16 + c];
        acc[t] = (f32x4){bv, bv, bv, bv};
    }
    #pragma unroll
    for (int t = 0; t < 8; ++t) {
        #pragma unroll
        for (int s = 0; s < 4; ++s) {
            bf16x8 bf = *(const bf16x8*)&W1t[(t * 16 + c) * DIM + s * 32 + g * 8];
            acc[t] = __builtin_amdgcn_mfma_f32_16x16x32_bf16(a[s], bf, acc[t], 0, 0, 0);
        }
    }
    __syncthreads();
    #pragma unroll
    for (int t = 0; t < 8; ++t)
        #pragma unroll
        for (int j = 0; j < 4; ++j)
            xs[wid][g * 4 + j][t * 16 + c] = f2bf(fmaxf(acc[t][j], 0.f));
    __syncthreads();

    #pragma unroll
    for (int s = 0; s < 4; ++s)
        a[s] = *(const bf16x8*)&xs[wid][c][s * 32 + g * 8];

    #pragma unroll
    for (int t = 0; t < 8; ++t) {
        float bv = b2[t * 16 + c];
        acc[t] = (f32x4){bv, bv, bv, bv};
    }
    #pragma unroll
    for (int t = 0; t < 8; ++t) {
        #pragma unroll
        for (int s = 0; s < 4; ++s) {
            bf16x8 bf = *(const bf16x8*)&W2t[(t * 16 + c) * DIM + s * 32 + g * 8];
            acc[t] = __builtin_amdgcn_mfma_f32_16x16x32_bf16(a[s], bf, acc[t], 0, 0, 0);
        }
    }

    #pragma unroll
    for (int j = 0; j < 4; ++j) {
        int r = load_idx(ei, i64, ebase + g * 4 + j);
        #pragma unroll
        for (int t = 0; t < 8; ++t)
            atomicAdd(&agg[(size_t)r * DIM + t * 16 + c], fmaxf(acc[t][j], 0.f));
    }
}

__global__ __launch_bounds__(256) void upd_kernel(
    const float* __restrict__ h, const float* __restrict__ aggout,
    const int* __restrict__ deg,
    const float* __restrict__ U1, const float* __restrict__ c1,
    const float* __restrict__ U2, const float* __restrict__ c2,
    float* __restrict__ out)
{
    __shared__ float zs[4][8][2 * DIM];   // 32 KiB
    const int tid  = threadIdx.x;
    const int lane = tid & 63;
    const int wid  = tid >> 6;
    const int nbase = blockIdx.x * 32 + wid * 8;

    #pragma unroll
    for (int i = 0; i < 8; ++i) {
        int n = nbase + i;
        if (n < NN) {
            float2 hv = *(const float2*)(h + (size_t)n * DIM + lane * 2);
            *(float2*)&zs[wid][i][lane * 2] = hv;
            float d = fmaxf((float)deg[n], 1.0f);
            float inv = 1.0f / d;
            float2 av = *(const float2*)(aggout + (size_t)n * DIM + lane * 2);
            av.x *= inv; av.y *= inv;
            *(float2*)&zs[wid][i][DIM + lane * 2] = av;
        }
    }
    __syncthreads();

    float acc0[8], acc1[8];
    {
        float cc0 = c1[lane], cc1 = c1[lane + 64];
        #pragma unroll
        for (int i = 0; i < 8; ++i) { acc0[i] = cc0; acc1[i] = cc1; }
    }
    for (int k = 0; k < 2 * DIM; k += 4) {
        float wa[4], wb[4];
        #pragma unroll
        for (int kk = 0; kk < 4; ++kk) {
            wa[kk] = U1[(k + kk) * DIM + lane];
            wb[kk] = U1[(k + kk) * DIM + lane + 64];
        }
        #pragma unroll
        for (int i = 0; i < 8; ++i) {
            float4 zv = *(const float4*)&zs[wid][i][k];
            acc0[i] = fmaf(zv.x, wa[0], acc0[i]);
            acc1[i] = fmaf(zv.x, wb[0], acc1[i]);
            acc0[i] = fmaf(zv.y, wa[1], acc0[i]);
            acc1[i] = fmaf(zv.y, wb[1], acc1[i]);
            acc0[i] = fmaf(zv.z, wa[2], acc0[i]);
            acc1[i] = fmaf(zv.z, wb[2], acc1[i]);
            acc0[i] = fmaf(zv.w, wa[3], acc0[i]);
            acc1[i] = fmaf(zv.w, wb[3], acc1[i]);
        }
    }
    __syncthreads();
    #pragma unroll
    for (int i = 0; i < 8; ++i) {
        zs[wid][i][lane]      = fmaxf(acc0[i], 0.f);
        zs[wid][i][lane + 64] = fmaxf(acc1[i], 0.f);
    }
    __syncthreads();

    {
        float cc0 = c2[lane], cc1 = c2[lane + 64];
        #pragma unroll
        for (int i = 0; i < 8; ++i) { acc0[i] = cc0; acc1[i] = cc1; }
    }
    for (int k = 0; k < DIM; k += 4) {
        float wa[4], wb[4];
        #pragma unroll
        for (int kk = 0; kk < 4; ++kk) {
            wa[kk] = U2[(k + kk) * DIM + lane];
            wb[kk] = U2[(k + kk) * DIM + lane + 64];
        }
        #pragma unroll
        for (int i = 0; i < 8; ++i) {
            float4 zv = *(const float4*)&zs[wid][i][k];
            acc0[i] = fmaf(zv.x, wa[0], acc0[i]);
            acc1[i] = fmaf(zv.x, wb[0], acc1[i]);
            acc0[i] = fmaf(zv.y, wa[1], acc0[i]);
            acc1[i] = fmaf(zv.y, wb[1], acc1[i]);
            acc0[i] = fmaf(zv.z, wa[2], acc0[i]);
            acc1[i] = fmaf(zv.z, wb[2], acc1[i]);
            acc0[i] = fmaf(zv.w, wa[3], acc0[i]);
            acc1[i] = fmaf(zv.w, wb[3], acc1[i]);
        }
    }

    #pragma unroll
    for (int i = 0; i < 8; ++i) {
        int n = nbase + i;
        if (n < NN) {
            out[(size_t)n * DIM + lane]      = acc0[i];
            out[(size_t)n * DIM + lane + 64] = acc1[i];
        }
    }
}

extern "C" void kernel_launch(void* const* d_in, const int* in_sizes, int n_in,
                              void* d_out, int out_size, void* d_ws, size_t ws_size,
                              hipStream_t stream) {
    const float* h  = (const float*)d_in[0];
    const void*  ei = d_in[1];
    const float* W1 = (const float*)d_in[2];
    const float* b1 = (const float*)d_in[3];
    const float* W2 = (const float*)d_in[4];
    const float* b2 = (const float*)d_in[5];
    const float* U1 = (const float*)d_in[6];
    const float* c1 = (const float*)d_in[7];
    const float* U2 = (const float*)d_in[8];
    const float* c2 = (const float*)d_in[9];
    float* out = (float*)d_out;

    // ws layout (big path):
    //   Mh    @ 0           bf16 [NN][128]   12,800,000 B
    //   col32 @ 12,800,000  int  [EE]         3,200,000 B
    //   deg   @ 16,000,000  int  [NN]           200,000 B
    //   off   @ 16,200,000  int  [NN]           200,000 B
    //   flag  @ 16,400,000  int                      64 B
    //   W1t   @ 16,400,064  bf16 [128][128]      32,768 B
    //   W2t   @ 16,432,832  bf16 [128][128]      32,768 B
    //   U1h   @ 16,465,600  bf16 [128][256]      65,536 B
    //   U1l   @ 16,531,136  bf16 [128][256]      65,536 B
    //   U2h   @ 16,596,672  bf16 [128][128]      32,768 B
    //   U2l   @ 16,629,440  bf16 [128][128]      32,768 B
    const size_t BIG_BYTES = 16662208;
    const bool big = ws_size >= BIG_BYTES;

    char* wsb = (char*)d_ws;
    unsigned short *Mh, *W1t, *W2t, *U1h, *U1l, *U2h, *U2l;
    int *col32, *deg, *off, *flag;
    if (big) {
        Mh    = (unsigned short*)wsb;
        col32 = (int*)(wsb + 12800000);
        deg   = (int*)(wsb + 16000000);
        off   = (int*)(wsb + 16200000);
        flag  = (int*)(wsb + 16400000);
        W1t   = (unsigned short*)(wsb + 16400064);
        W2t   = (unsigned short*)(wsb + 16432832);
        U1h   = (unsigned short*)(wsb + 16465600);
        U1l   = (unsigned short*)(wsb + 16531136);
        U2h   = (unsigned short*)(wsb + 16596672);
        U2l   = (unsigned short*)(wsb + 16629440);
    } else {
        Mh    = nullptr; col32 = nullptr;
        U1h = U1l = U2h = U2l = nullptr;
        deg   = (int*)wsb;
        off   = (int*)(wsb + 200000);
        flag  = (int*)(wsb + 400000);
        W1t   = (unsigned short*)(wsb + 400064);
        W2t   = (unsigned short*)(wsb + 400064 + 32768);
    }

    if (big) {
        prep_zero_kernel<<<PREP_BLKS + ZERO_BLKS, 256, 0, stream>>>(
            W1, W2, U1, U2, W1t, W2t, U1h, U1l, U2h, U2l, deg);
        deg_fast_kernel<<<FILL_BLKS, 256, 0, stream>>>(ei, deg);
        scan_kernel<<<1, 1024, 0, stream>>>(deg, off);
        fill_mlp_kernel<<<FILL_BLKS + MLP_BLKS, 256, 0, stream>>>(
            ei, h, W1t, b1, W2t, b2, off, col32, Mh);
        gup_kernel<<<MLP_BLKS, 256, 0, stream>>>(h, Mh, col32, off, deg,
                                                 U1h, U1l, U2h, U2l, c1, c2, out);
    } else {
        detect_i64_kernel<<<1, 64, 0, stream>>>((const int*)ei, flag);
        prep_w_kernel<<<128, 256, 0, stream>>>(W1, W2, W1t, W2t);
        hipMemsetAsync(deg, 0, (size_t)NN * sizeof(int), stream);
        deg_i_kernel<<<(EE + 255) / 256, 256, 0, stream>>>(ei, flag, deg);
        hipMemsetAsync(d_out, 0, (size_t)NN * DIM * sizeof(float), stream);
        msg_kernel<<<EE / 64, 256, 0, stream>>>(h, ei, flag, W1t, b1, W2t, b2, out);
        upd_kernel<<<(NN + 31) / 32, 256, 0, stream>>>(h, out, deg, U1, c1, U2, c2, out);
    }
}